// Round 8
// baseline (168.633 us; speedup 1.0000x reference)
//
#include <hip/hip_runtime.h>
#include <math.h>

#define NN 2048
#define PP 4096
#define DD 128
#define SS 150
#define THR 204
#define ROWS 8
#define TPB 512
#define CAP 512
#define EXP2C 2.8853900817779268f   // 2/ln(2): exp(2x) = 2^(EXP2C*x)

typedef float f32x4 __attribute__((ext_vector_type(4)));
typedef short s16x8 __attribute__((ext_vector_type(8)));

// ws layout (float offsets)
#define OFF_POOLN 0
#define OFF_POOLT 524288
#define OFF_WTT   1048576   // 16384 floats (W^T, [k][d])
#define OFF_PROJ  1064960   // 4096*128 floats = z_pool @ W^T
#define OFF_NEG   1589248
#define OFF_REFL  1593344
#define OFF_POSD  1597440
#define OFF_TOPI  1601536   // 4096*204 ints
#define OFF_POOLB 2437120   // 4096*128 bf16 (ushort) = 262144 floats
#define OFF_SIMS  2699264   // 4096*4096 u32 keys = 64 MB
#define WS_FAST_FLOATS (OFF_SIMS + (size_t)PP * PP)

// ---------------- prep: normalize pool rows; fp32 row-major + fp32 transposed + bf16 ----------------
__global__ void prep_norm(const float* __restrict__ z1, const float* __restrict__ z2,
                          float* __restrict__ pool_n, float* __restrict__ pool_nT,
                          unsigned short* __restrict__ poolb) {
    int b = blockIdx.x;          // pool row 0..4095
    int l = threadIdx.x;         // 0..63
    const float* src = (b < NN) ? z1 + (size_t)b * DD : z2 + (size_t)(b - NN) * DD;
    float2 v = *(const float2*)(src + 2 * l);
    float ss = v.x * v.x + v.y * v.y;
    #pragma unroll
    for (int mask = 1; mask < 64; mask <<= 1) ss += __shfl_xor(ss, mask);
    float inv = 1.0f / fmaxf(sqrtf(ss), 1e-12f);
    float2 nv; nv.x = v.x * inv; nv.y = v.y * inv;
    *(float2*)(pool_n + (size_t)b * DD + 2 * l) = nv;
    pool_nT[(size_t)(2 * l) * PP + b]     = nv.x;
    pool_nT[(size_t)(2 * l + 1) * PP + b] = nv.y;
    // bf16 RNE pack
    unsigned ux = __float_as_uint(nv.x); ux = (ux + 0x7FFFu + ((ux >> 16) & 1u)) >> 16;
    unsigned uy = __float_as_uint(nv.y); uy = (uy + 0x7FFFu + ((uy >> 16) & 1u)) >> 16;
    ((unsigned*)poolb)[(size_t)b * 64 + l] = ux | (uy << 16);
}

// ---------------- prep: transpose proj_w (fp32), layout [k][d] ----------------
__global__ void prep_wt(const float* __restrict__ pw, float* __restrict__ wtT) {
    int e = blockIdx.x * 256 + threadIdx.x;   // 0..16383
    int k = e >> 7, d = e & 127;
    wtT[e] = pw[d * DD + k];
}

// ---------------- prep: P = z_pool @ W^T (no bias) ----------------
__global__ __launch_bounds__(256, 4) void prep_proj(
    const float* __restrict__ z1, const float* __restrict__ z2,
    const float* __restrict__ wtT, float* __restrict__ P) {
    __shared__ float z_sh[8][DD];
    int tid = threadIdx.x;
    int r0 = blockIdx.x * 8;
    for (int e = tid; e < 8 * DD; e += 256) {
        int rr = r0 + (e >> 7);
        z_sh[e >> 7][e & 127] = (rr < NN) ? z1[(size_t)rr * DD + (e & 127)]
                                          : z2[(size_t)(rr - NN) * DD + (e & 127)];
    }
    __syncthreads();
    int d = tid & 127, h = tid >> 7;
    float a0 = 0.f, a1 = 0.f, a2 = 0.f, a3 = 0.f;
    for (int k = 0; k < DD; k++) {
        float wv = wtT[k * DD + d];
        a0 += z_sh[4 * h + 0][k] * wv;
        a1 += z_sh[4 * h + 1][k] * wv;
        a2 += z_sh[4 * h + 2][k] * wv;
        a3 += z_sh[4 * h + 3][k] * wv;
    }
    P[(size_t)(r0 + 4 * h + 0) * DD + d] = a0;
    P[(size_t)(r0 + 4 * h + 1) * DD + d] = a1;
    P[(size_t)(r0 + 4 * h + 2) * DD + d] = a2;
    P[(size_t)(r0 + 4 * h + 3) * DD + d] = a3;
}

// order-preserving float->uint key (larger float => larger key)
__device__ __forceinline__ unsigned fkey(float v) {
    unsigned u = __float_as_uint(v);
    return u ^ (unsigned)(((int)u >> 31) | 0x80000000);
}

// ---------------- FAST PATH A: keys = fkey(poolb @ poolb^T) via MFMA; fused negsum/refl/posd ----------------
#define LDA 136   // shorts per LDS row (128 + 8 pad)
__global__ __launch_bounds__(256) void gram_mfma(
    const unsigned short* __restrict__ poolb, unsigned* __restrict__ simsk,
    float* __restrict__ negsum, float* __restrict__ refl, float* __restrict__ posd) {
    __shared__ short tiles[2 * 128 * LDA];   // 69.6 KB
    short* As = tiles;
    short* Bs = tiles + 128 * LDA;

    int tid = threadIdx.x;
    int bi = blockIdx.x >> 5, bj = blockIdx.x & 31;
    int r0 = bi * 128, c0 = bj * 128;

    const unsigned short* gA = poolb + (size_t)r0 * DD;
    const unsigned short* gB = poolb + (size_t)c0 * DD;
    #pragma unroll
    for (int it = 0; it < 8; it++) {
        int g = it * 256 + tid;
        int row = g >> 4, ch = (g & 15) * 8;
        *(s16x8*)&As[row * LDA + ch] = *(const s16x8*)(gA + row * DD + ch);
        *(s16x8*)&Bs[row * LDA + ch] = *(const s16x8*)(gB + row * DD + ch);
    }
    __syncthreads();

    int l = tid & 63, w = tid >> 6;
    int wr = (w >> 1) * 64, wc = (w & 1) * 64;
    int lr = l & 15, lk = (l >> 4) * 8;

    f32x4 zero = {0.f, 0.f, 0.f, 0.f};
    f32x4 acc[4][4];
    #pragma unroll
    for (int m = 0; m < 4; m++)
        #pragma unroll
        for (int n = 0; n < 4; n++) acc[m][n] = zero;

    #pragma unroll
    for (int kk = 0; kk < 4; kk++) {
        int ko = kk * 32 + lk;
        s16x8 av[4], bv[4];
        #pragma unroll
        for (int m = 0; m < 4; m++)
            av[m] = *(const s16x8*)&As[(wr + m * 16 + lr) * LDA + ko];
        #pragma unroll
        for (int n = 0; n < 4; n++)
            bv[n] = *(const s16x8*)&Bs[(wc + n * 16 + lr) * LDA + ko];
        #pragma unroll
        for (int m = 0; m < 4; m++)
            #pragma unroll
            for (int n = 0; n < 4; n++)
                acc[m][n] = __builtin_amdgcn_mfma_f32_16x16x32_bf16(av[m], bv[n], acc[m][n], 0, 0, 0);
    }

    int fq = (l >> 4) * 4, fr = l & 15;

    // fused negsum: per (m,reg), sum exp over this wave's 64 cols, reduce over 16 lanes
    #pragma unroll
    for (int m = 0; m < 4; m++)
        #pragma unroll
        for (int reg = 0; reg < 4; reg++) {
            float es = __builtin_exp2f(EXP2C * acc[m][0][reg])
                     + __builtin_exp2f(EXP2C * acc[m][1][reg])
                     + __builtin_exp2f(EXP2C * acc[m][2][reg])
                     + __builtin_exp2f(EXP2C * acc[m][3][reg]);
            es += __shfl_xor(es, 1);
            es += __shfl_xor(es, 2);
            es += __shfl_xor(es, 4);
            es += __shfl_xor(es, 8);
            if (fr == 0) atomicAdd(&negsum[r0 + wr + m * 16 + fq + reg], es);
        }

    // key write: row = grow+reg, col = gcol
    #pragma unroll
    for (int m = 0; m < 4; m++)
        #pragma unroll
        for (int n = 0; n < 4; n++) {
            int grow = r0 + wr + m * 16 + fq;
            int gcol = c0 + wc + n * 16 + fr;
            size_t base = (size_t)grow * PP + gcol;
            #pragma unroll
            for (int reg = 0; reg < 4; reg++)
                simsk[base + (size_t)reg * PP] = fkey(acc[m][n][reg]);
        }

    // refl / posd only on the 64 blocks that contain them (uniform branch)
    if (r0 == c0 || c0 == (r0 ^ NN)) {
        #pragma unroll
        for (int m = 0; m < 4; m++)
            #pragma unroll
            for (int n = 0; n < 4; n++) {
                int grow = r0 + wr + m * 16 + fq;
                int gcol = c0 + wc + n * 16 + fr;
                #pragma unroll
                for (int reg = 0; reg < 4; reg++) {
                    float v = acc[m][n][reg];
                    if (gcol == grow + reg) refl[gcol] = v;
                    if (gcol == ((grow + reg) ^ NN)) posd[grow + reg] = v;
                }
            }
    }
}

// ---------------- FAST PATH B: top-204 select over key rows ----------------
__global__ __launch_bounds__(256) void rowselect(
    const unsigned* __restrict__ keys, int* __restrict__ topidx) {
    __shared__ int hist[2][256];         // split to halve same-address atomic contention
    __shared__ uint2 cand[CAP];
    __shared__ int scal[4];   // 0:B  1:cum  2:P16  3:cnt

    int tid = threadIdx.x, w = tid >> 6, l = tid & 63;
    int hs = w >> 1;
    int r = blockIdx.x;
    const uint4* rp = (const uint4*)(keys + (size_t)r * PP);

    uint4 va[4];
    #pragma unroll
    for (int j = 0; j < 4; j++) va[j] = rp[tid + j * 256];

    hist[0][tid] = 0; hist[1][tid] = 0;
    if (tid == 0) scal[3] = 0;
    __syncthreads();

    // hist1 on key[31:24]
    #pragma unroll
    for (int j = 0; j < 4; j++) {
        atomicAdd(&hist[hs][va[j].x >> 24], 1);
        atomicAdd(&hist[hs][va[j].y >> 24], 1);
        atomicAdd(&hist[hs][va[j].z >> 24], 1);
        atomicAdd(&hist[hs][va[j].w >> 24], 1);
    }
    __syncthreads();
    if (w == 0) {
        int4 ha = ((const int4*)hist[0])[l];
        int4 hb = ((const int4*)hist[1])[l];
        int4 h4 = make_int4(ha.x + hb.x, ha.y + hb.y, ha.z + hb.z, ha.w + hb.w);
        int s = h4.x + h4.y + h4.z + h4.w;
        int suf = s;
        #pragma unroll
        for (int off = 1; off < 64; off <<= 1) {
            int x = __shfl_down(suf, off);
            if (l + off < 64) suf += x;
        }
        int A = suf - s;
        int ca3 = A, ca2 = A + h4.w, ca1 = ca2 + h4.z, ca0 = ca1 + h4.y;
        if (ca3 < THR && THR <= ca3 + h4.w) { scal[0] = 4 * l + 3; scal[1] = ca3; }
        if (ca2 < THR && THR <= ca2 + h4.z) { scal[0] = 4 * l + 2; scal[1] = ca2; }
        if (ca1 < THR && THR <= ca1 + h4.y) { scal[0] = 4 * l + 1; scal[1] = ca1; }
        if (ca0 < THR && THR <= ca0 + h4.x) { scal[0] = 4 * l + 0; scal[1] = ca0; }
    }
    __syncthreads();
    unsigned B = (unsigned)scal[0];
    int base = scal[1];
    hist[0][tid] = 0; hist[1][tid] = 0;
    __syncthreads();

    // hist2 on key[23:16] within bin B
    #pragma unroll
    for (int j = 0; j < 4; j++) {
        #pragma unroll
        for (int c = 0; c < 4; c++) {
            unsigned key = (c == 0) ? va[j].x : (c == 1) ? va[j].y : (c == 2) ? va[j].z : va[j].w;
            if ((key >> 24) == B) atomicAdd(&hist[hs][(key >> 16) & 255], 1);
        }
    }
    __syncthreads();
    if (w == 0) {
        int4 ha = ((const int4*)hist[0])[l];
        int4 hb = ((const int4*)hist[1])[l];
        int4 h4 = make_int4(ha.x + hb.x, ha.y + hb.y, ha.z + hb.z, ha.w + hb.w);
        int s = h4.x + h4.y + h4.z + h4.w;
        int suf = s;
        #pragma unroll
        for (int off = 1; off < 64; off <<= 1) {
            int x = __shfl_down(suf, off);
            if (l + off < 64) suf += x;
        }
        int A = base + suf - s;
        int ca3 = A, ca2 = A + h4.w, ca1 = ca2 + h4.z, ca0 = ca1 + h4.y;
        if (ca3 < THR && THR <= ca3 + h4.w) scal[2] = (int)((B << 8) | (4 * l + 3));
        if (ca2 < THR && THR <= ca2 + h4.z) scal[2] = (int)((B << 8) | (4 * l + 2));
        if (ca1 < THR && THR <= ca1 + h4.y) scal[2] = (int)((B << 8) | (4 * l + 1));
        if (ca0 < THR && THR <= ca0 + h4.x) scal[2] = (int)((B << 8) | (4 * l + 0));
    }
    __syncthreads();
    unsigned P16 = (unsigned)scal[2];

    // collect candidates
    #pragma unroll
    for (int j = 0; j < 4; j++) {
        int col0 = (tid + j * 256) * 4;
        #pragma unroll
        for (int c = 0; c < 4; c++) {
            unsigned key = (c == 0) ? va[j].x : (c == 1) ? va[j].y : (c == 2) ? va[j].z : va[j].w;
            if ((key >> 16) >= P16) {
                int p = atomicAdd(&scal[3], 1);
                if (p < CAP) cand[p] = make_uint2(key, (unsigned)(col0 + c));
            }
        }
    }
    __syncthreads();

    // rank (key desc, col asc)
    int C = min(scal[3], CAP);
    #pragma unroll
    for (int o = 0; o < 2; o++) {
        int t = tid + o * 256;
        if (t < C) {
            uint2 me = cand[t];
            int rk = 0;
            for (int c = 0; c < C; c++) {
                uint2 cd = cand[c];
                rk += (cd.x > me.x || (cd.x == me.x && (int)cd.y < (int)me.y)) ? 1 : 0;
            }
            if (rk < THR) topidx[(size_t)r * THR + rk] = (int)me.y;
        }
    }
}

// ---------------- FALLBACK: round-4 fused gram+select (used if ws too small) ----------------
__global__ __launch_bounds__(TPB, 4) void simtopk(
    const float* __restrict__ pool_n, const float* __restrict__ pool_nT,
    float* __restrict__ negsum, float* __restrict__ refl, float* __restrict__ posd,
    int* __restrict__ topidx) {
    __shared__ float q_sh[ROWS][DD];
    __shared__ int hist[ROWS][256];
    __shared__ uint2 cand[ROWS][CAP];
    __shared__ int rowB[ROWS], rowCum[ROWS], rowP[ROWS], cnt[ROWS];
    __shared__ float partial[ROWS][8];

    int tid = threadIdx.x, w = tid >> 6, l = tid & 63;
    int r0 = blockIdx.x * ROWS;

    for (int e = tid; e < ROWS * DD; e += TPB)
        q_sh[e >> 7][e & 127] = pool_n[(size_t)r0 * DD + e];
    __syncthreads();

    float acc[ROWS][8];
    #pragma unroll
    for (int r = 0; r < ROWS; r++)
        #pragma unroll
        for (int e = 0; e < 8; e++) acc[r][e] = 0.f;

    const float4* pt4 = (const float4*)pool_nT;
    for (int k = 0; k < DD; k++) {
        float4 p0 = pt4[k * 1024 + tid];
        float4 p1 = pt4[k * 1024 + 512 + tid];
        #pragma unroll
        for (int r = 0; r < ROWS; r++) {
            float qk = q_sh[r][k];
            acc[r][0] += qk * p0.x; acc[r][1] += qk * p0.y; acc[r][2] += qk * p0.z; acc[r][3] += qk * p0.w;
            acc[r][4] += qk * p1.x; acc[r][5] += qk * p1.y; acc[r][6] += qk * p1.z; acc[r][7] += qk * p1.w;
        }
    }

    #pragma unroll
    for (int r = 0; r < ROWS; r++) {
        int rg = r0 + r;
        float es = 0.f;
        #pragma unroll
        for (int e = 0; e < 8; e++) {
            es += __builtin_exp2f(EXP2C * acc[r][e]);
            int col = (e >> 2) * 2048 + (tid << 2) + (e & 3);
            if (col == rg) refl[rg] = acc[r][e];
            if (col == (rg ^ NN)) posd[rg] = acc[r][e];
        }
        #pragma unroll
        for (int mask = 1; mask < 64; mask <<= 1) es += __shfl_xor(es, mask);
        if (l == 0) partial[r][w] = es;
    }

    for (int e = tid; e < ROWS * 256; e += TPB) ((int*)hist)[e] = 0;
    if (tid < ROWS) cnt[tid] = 0;
    __syncthreads();
    if (tid < ROWS) {
        float s = 0.f;
        #pragma unroll
        for (int ww = 0; ww < 8; ww++) s += partial[tid][ww];
        negsum[r0 + tid] = s;
    }
    #pragma unroll
    for (int r = 0; r < ROWS; r++)
        #pragma unroll
        for (int e = 0; e < 8; e++)
            atomicAdd(&hist[r][fkey(acc[r][e]) >> 24], 1);
    __syncthreads();

    {
        int rr = w;
        int4 h4 = ((const int4*)hist[rr])[l];
        int s = h4.x + h4.y + h4.z + h4.w;
        int suf = s;
        #pragma unroll
        for (int off = 1; off < 64; off <<= 1) {
            int x = __shfl_down(suf, off);
            if (l + off < 64) suf += x;
        }
        int A = suf - s;
        int ca3 = A, ca2 = A + h4.w, ca1 = ca2 + h4.z, ca0 = ca1 + h4.y;
        if (ca3 < THR && THR <= ca3 + h4.w) { rowB[rr] = 4 * l + 3; rowCum[rr] = ca3; }
        if (ca2 < THR && THR <= ca2 + h4.z) { rowB[rr] = 4 * l + 2; rowCum[rr] = ca2; }
        if (ca1 < THR && THR <= ca1 + h4.y) { rowB[rr] = 4 * l + 1; rowCum[rr] = ca1; }
        if (ca0 < THR && THR <= ca0 + h4.x) { rowB[rr] = 4 * l + 0; rowCum[rr] = ca0; }
    }
    __syncthreads();

    for (int e = tid; e < ROWS * 256; e += TPB) ((int*)hist)[e] = 0;
    __syncthreads();
    #pragma unroll
    for (int r = 0; r < ROWS; r++) {
        int B = rowB[r];
        #pragma unroll
        for (int e = 0; e < 8; e++) {
            unsigned key = fkey(acc[r][e]);
            if ((int)(key >> 24) == B) atomicAdd(&hist[r][(key >> 16) & 255], 1);
        }
    }
    __syncthreads();

    {
        int rr = w;
        int base = rowCum[rr];
        int4 h4 = ((const int4*)hist[rr])[l];
        int s = h4.x + h4.y + h4.z + h4.w;
        int suf = s;
        #pragma unroll
        for (int off = 1; off < 64; off <<= 1) {
            int x = __shfl_down(suf, off);
            if (l + off < 64) suf += x;
        }
        int A = base + suf - s;
        int ca3 = A, ca2 = A + h4.w, ca1 = ca2 + h4.z, ca0 = ca1 + h4.y;
        if (ca3 < THR && THR <= ca3 + h4.w) rowP[rr] = (rowB[rr] << 8) | (4 * l + 3);
        if (ca2 < THR && THR <= ca2 + h4.z) rowP[rr] = (rowB[rr] << 8) | (4 * l + 2);
        if (ca1 < THR && THR <= ca1 + h4.y) rowP[rr] = (rowB[rr] << 8) | (4 * l + 1);
        if (ca0 < THR && THR <= ca0 + h4.x) rowP[rr] = (rowB[rr] << 8) | (4 * l + 0);
    }
    __syncthreads();

    #pragma unroll
    for (int r = 0; r < ROWS; r++) {
        unsigned P16 = (unsigned)rowP[r];
        #pragma unroll
        for (int e = 0; e < 8; e++) {
            unsigned key = fkey(acc[r][e]);
            if ((key >> 16) >= P16) {
                int p = atomicAdd(&cnt[r], 1);
                if (p < CAP) {
                    int col = (e >> 2) * 2048 + (tid << 2) + (e & 3);
                    cand[r][p] = make_uint2(key, (unsigned)col);
                }
            }
        }
    }
    __syncthreads();

    {
        int rr = w;
        int C = min(cnt[rr], CAP);
        int rg = r0 + rr;
        unsigned km[8]; int im[8], rk[8];
        #pragma unroll
        for (int o = 0; o < 8; o++) {
            int b = l + o * 64;
            bool v = (b < C);
            uint2 cd = v ? cand[rr][b] : make_uint2(0u, 0u);
            km[o] = cd.x; im[o] = (int)cd.y; rk[o] = v ? 0 : (THR + CAP);
        }
        for (int c = 0; c < C; c++) {
            uint2 cd = cand[rr][c];
            unsigned kc = cd.x; int ic = (int)cd.y;
            #pragma unroll
            for (int o = 0; o < 8; o++)
                if (o * 64 < C)
                    rk[o] += (kc > km[o] || (kc == km[o] && ic < im[o])) ? 1 : 0;
        }
        #pragma unroll
        for (int o = 0; o < 8; o++)
            if (rk[o] < THR) topidx[(size_t)rg * THR + rk[o]] = im[o];
    }
}

// ---------------- mix + normalize + dot + loss; shuffle-free main loop ----------------
__global__ __launch_bounds__(256) void mixloss(
    const float* __restrict__ P, const float* __restrict__ pool_n,
    const float* __restrict__ proj_b,
    const float* __restrict__ negsum, const float* __restrict__ refl,
    const float* __restrict__ posd, const int* __restrict__ topidx,
    const int* __restrict__ idx1, const int* __restrict__ idx2,
    float* __restrict__ out) {
    __shared__ int top_sh[THR];
    __shared__ int idx_sh[2 * SS];
    __shared__ float pn2[SS * 17];       // stride 17: bank-spread
    __shared__ float pdt[SS * 17];
    __shared__ float red2[4];

    int tid = threadIdx.x, w = tid >> 6, l = tid & 63;
    int r = blockIdx.x;
    int i = r & (NN - 1);
    const int* idxp = ((r >= NN) ? idx2 : idx1) + (size_t)i * (2 * SS);

    if (tid < THR) top_sh[tid] = topidx[(size_t)r * THR + tid];
    for (int e = tid; e < 2 * SS; e += 256) idx_sh[e] = idxp[e];
    __syncthreads();

    int g = l >> 4, sub = l & 15, d0 = sub * 8;
    float4 qa = *(const float4*)(pool_n + (size_t)r * DD + d0);
    float4 qb = *(const float4*)(pool_n + (size_t)r * DD + d0 + 4);
    float4 ba = *(const float4*)(proj_b + d0);
    float4 bb = *(const float4*)(proj_b + d0 + 4);

    // phase 1: lane partials only, no cross-lane ops
    for (int it = w; it < 19; it += 4) {
        int p = it * 4 + g;
        if (p < 75) {
            int t = 2 * p;
            int c1a = top_sh[idx_sh[t]],     c2a = top_sh[idx_sh[t + SS]];
            int c1b = top_sh[idx_sh[t + 1]], c2b = top_sh[idx_sh[t + 1 + SS]];
            const float* pa1 = P + (size_t)c1a * DD + d0;
            const float* pa2 = P + (size_t)c2a * DD + d0;
            const float* pb1 = P + (size_t)c1b * DD + d0;
            const float* pb2 = P + (size_t)c2b * DD + d0;
            float4 xa0 = *(const float4*)pa1;
            float4 xa1 = *(const float4*)(pa1 + 4);
            float4 ya0 = *(const float4*)pa2;
            float4 ya1 = *(const float4*)(pa2 + 4);
            float4 xb0 = *(const float4*)pb1;
            float4 xb1 = *(const float4*)(pb1 + 4);
            float4 yb0 = *(const float4*)pb2;
            float4 yb1 = *(const float4*)(pb2 + 4);

            float a0 = fmaf(0.2f, xa0.x, fmaf(0.8f, ya0.x, ba.x));
            float a1 = fmaf(0.2f, xa0.y, fmaf(0.8f, ya0.y, ba.y));
            float a2 = fmaf(0.2f, xa0.z, fmaf(0.8f, ya0.z, ba.z));
            float a3 = fmaf(0.2f, xa0.w, fmaf(0.8f, ya0.w, ba.w));
            float a4 = fmaf(0.2f, xa1.x, fmaf(0.8f, ya1.x, bb.x));
            float a5 = fmaf(0.2f, xa1.y, fmaf(0.8f, ya1.y, bb.y));
            float a6 = fmaf(0.2f, xa1.z, fmaf(0.8f, ya1.z, bb.z));
            float a7 = fmaf(0.2f, xa1.w, fmaf(0.8f, ya1.w, bb.w));
            float b0 = fmaf(0.2f, xb0.x, fmaf(0.8f, yb0.x, ba.x));
            float b1 = fmaf(0.2f, xb0.y, fmaf(0.8f, yb0.y, ba.y));
            float b2 = fmaf(0.2f, xb0.z, fmaf(0.8f, yb0.z, ba.z));
            float b3 = fmaf(0.2f, xb0.w, fmaf(0.8f, yb0.w, ba.w));
            float b4 = fmaf(0.2f, xb1.x, fmaf(0.8f, yb1.x, bb.x));
            float b5 = fmaf(0.2f, xb1.y, fmaf(0.8f, yb1.y, bb.y));
            float b6 = fmaf(0.2f, xb1.z, fmaf(0.8f, yb1.z, bb.z));
            float b7 = fmaf(0.2f, xb1.w, fmaf(0.8f, yb1.w, bb.w));

            float n2a = a0*a0 + a1*a1 + a2*a2 + a3*a3 + a4*a4 + a5*a5 + a6*a6 + a7*a7;
            float dta = a0*qa.x + a1*qa.y + a2*qa.z + a3*qa.w
                      + a4*qb.x + a5*qb.y + a6*qb.z + a7*qb.w;
            float n2b = b0*b0 + b1*b1 + b2*b2 + b3*b3 + b4*b4 + b5*b5 + b6*b6 + b7*b7;
            float dtb = b0*qa.x + b1*qa.y + b2*qa.z + b3*qa.w
                      + b4*qb.x + b5*qb.y + b6*qb.z + b7*qb.w;
            pn2[t * 17 + sub] = n2a;
            pdt[t * 17 + sub] = dta;
            pn2[(t + 1) * 17 + sub] = n2b;
            pdt[(t + 1) * 17 + sub] = dtb;
        }
    }
    __syncthreads();

    // phase 2: thread t reduces its 16 partials
    float wsum = 0.f;
    if (tid < SS) {
        float n2 = 0.f, dt = 0.f;
        #pragma unroll
        for (int k = 0; k < 16; k++) {
            n2 += pn2[tid * 17 + k];
            dt += pdt[tid * 17 + k];
        }
        wsum = __builtin_exp2f(EXP2C * dt * rsqrtf(fmaxf(n2, 1e-24f)));
    }
    #pragma unroll
    for (int mask = 1; mask < 64; mask <<= 1) wsum += __shfl_xor(wsum, mask);
    if (l == 0) red2[w] = wsum;
    __syncthreads();
    if (tid == 0) {
        float negm = red2[0] + red2[1] + red2[2] + red2[3];
        float den = negsum[r] + negm - refl[r];
        float loss = logf(den) - 2.0f * posd[r];
        atomicAdd(out, loss * (1.0f / 4096.0f));
    }
}

extern "C" void kernel_launch(void* const* d_in, const int* in_sizes, int n_in,
                              void* d_out, int out_size, void* d_ws, size_t ws_size,
                              hipStream_t stream) {
    const float* z1  = (const float*)d_in[0];
    const float* z2  = (const float*)d_in[1];
    const float* pw  = (const float*)d_in[2];
    const float* pb  = (const float*)d_in[3];
    const int* idx1  = (const int*)d_in[4];
    const int* idx2  = (const int*)d_in[5];
    float* out = (float*)d_out;

    float* wsf = (float*)d_ws;
    float* pool_n  = wsf + OFF_POOLN;
    float* pool_nT = wsf + OFF_POOLT;
    float* wtT     = wsf + OFF_WTT;
    float* Pm      = wsf + OFF_PROJ;
    float* negs    = wsf + OFF_NEG;
    float* rfl     = wsf + OFF_REFL;
    float* psd     = wsf + OFF_POSD;
    int*   topi    = (int*)(wsf + OFF_TOPI);
    unsigned short* poolb = (unsigned short*)(wsf + OFF_POOLB);
    unsigned* simsk = (unsigned*)(wsf + OFF_SIMS);

    hipMemsetAsync(d_out, 0, sizeof(float), stream);
    hipMemsetAsync(negs, 0, PP * sizeof(float), stream);

    prep_norm<<<PP, 64, 0, stream>>>(z1, z2, pool_n, pool_nT, poolb);
    prep_wt<<<64, 256, 0, stream>>>(pw, wtT);
    prep_proj<<<PP / 8, 256, 0, stream>>>(z1, z2, wtT, Pm);

    if (ws_size >= WS_FAST_FLOATS * sizeof(float)) {
        gram_mfma<<<1024, 256, 0, stream>>>(poolb, simsk, negs, rfl, psd);
        rowselect<<<PP, 256, 0, stream>>>(simsk, topi);
    } else {
        simtopk<<<PP / ROWS, TPB, 0, stream>>>(pool_n, pool_nT, negs, rfl, psd, topi);
    }
    mixloss<<<PP, 256, 0, stream>>>(Pm, pool_n, pb, negs, rfl, psd, topi,
                                    idx1, idx2, out);
}

// Round 10
// 149.418 us; speedup vs baseline: 1.1286x; 1.1286x over previous
//
#include <hip/hip_runtime.h>
#include <math.h>

#define NN 2048
#define PP 4096
#define DD 128
#define SS 150
#define THR 204
#define CAP 512
#define EXP2C 2.8853900817779268f   // 2/ln(2): exp(2x) = 2^(EXP2C*x)

typedef float f32x4 __attribute__((ext_vector_type(4)));
typedef short s16x8 __attribute__((ext_vector_type(8)));

// ws layout (float offsets) — bf16 arrays are 4096*128 u16 = 262144 floats each
#define OFF_POOLN 0          // 524288 f32
#define OFF_WTT   524288     // 16384 f32
#define OFF_PB    540672     // 262144 floats (bf16 projected pool)
#define OFF_NEG   802816     // 4096
#define OFF_REFL  806912     // 4096
#define OFF_POSD  811008     // 4096
#define OFF_TOPI  815104     // 835584 ints
#define OFF_POOLB 1650688    // 262144 floats (bf16 normalized pool)
#define OFF_SIMS  1912832    // 4096*4096 u32 keys = 64 MB

__device__ __forceinline__ unsigned fkey(float v) {
    unsigned u = __float_as_uint(v);
    return u ^ (unsigned)(((int)u >> 31) | 0x80000000);
}
__device__ __forceinline__ float fkinv(unsigned k) {
    unsigned u = (k & 0x80000000u) ? (k ^ 0x80000000u) : ~k;
    return __uint_as_float(u);
}
__device__ __forceinline__ unsigned short f2bf(float f) {
    unsigned u = __float_as_uint(f);
    u = (u + 0x7FFFu + ((u >> 16) & 1u)) >> 16;
    return (unsigned short)u;
}
__device__ __forceinline__ float bf2f(unsigned short h) {
    return __uint_as_float((unsigned)h << 16);
}

// ---------------- prep: normalize pool rows -> f32 + bf16 ----------------
__global__ void prep_norm(const float* __restrict__ z1, const float* __restrict__ z2,
                          float* __restrict__ pool_n, unsigned short* __restrict__ poolb) {
    int b = blockIdx.x;
    int l = threadIdx.x;
    const float* src = (b < NN) ? z1 + (size_t)b * DD : z2 + (size_t)(b - NN) * DD;
    float2 v = *(const float2*)(src + 2 * l);
    float ss = v.x * v.x + v.y * v.y;
    #pragma unroll
    for (int mask = 1; mask < 64; mask <<= 1) ss += __shfl_xor(ss, mask);
    float inv = 1.0f / fmaxf(sqrtf(ss), 1e-12f);
    float2 nv; nv.x = v.x * inv; nv.y = v.y * inv;
    *(float2*)(pool_n + (size_t)b * DD + 2 * l) = nv;
    ((unsigned*)poolb)[(size_t)b * 64 + l] =
        (unsigned)f2bf(nv.x) | ((unsigned)f2bf(nv.y) << 16);
}

// ---------------- prep: transpose proj_w (fp32), layout [k][d] ----------------
__global__ void prep_wt(const float* __restrict__ pw, float* __restrict__ wtT) {
    int e = blockIdx.x * 256 + threadIdx.x;
    int k = e >> 7, d = e & 127;
    wtT[e] = pw[d * DD + k];
}

// ---------------- prep: Pb = bf16(z_pool @ W^T) ----------------
__global__ __launch_bounds__(256, 4) void prep_proj(
    const float* __restrict__ z1, const float* __restrict__ z2,
    const float* __restrict__ wtT, unsigned short* __restrict__ Pb) {
    __shared__ float z_sh[8][DD];
    int tid = threadIdx.x;
    int r0 = blockIdx.x * 8;
    for (int e = tid; e < 8 * DD; e += 256) {
        int rr = r0 + (e >> 7);
        z_sh[e >> 7][e & 127] = (rr < NN) ? z1[(size_t)rr * DD + (e & 127)]
                                          : z2[(size_t)(rr - NN) * DD + (e & 127)];
    }
    __syncthreads();
    int d = tid & 127, h = tid >> 7;
    float a0 = 0.f, a1 = 0.f, a2 = 0.f, a3 = 0.f;
    for (int k = 0; k < DD; k++) {
        float wv = wtT[k * DD + d];
        a0 += z_sh[4 * h + 0][k] * wv;
        a1 += z_sh[4 * h + 1][k] * wv;
        a2 += z_sh[4 * h + 2][k] * wv;
        a3 += z_sh[4 * h + 3][k] * wv;
    }
    Pb[(size_t)(r0 + 4 * h + 0) * DD + d] = f2bf(a0);
    Pb[(size_t)(r0 + 4 * h + 1) * DD + d] = f2bf(a1);
    Pb[(size_t)(r0 + 4 * h + 2) * DD + d] = f2bf(a2);
    Pb[(size_t)(r0 + 4 * h + 3) * DD + d] = f2bf(a3);
}

// ---------------- MFMA gram -> order-preserving keys; refl/posd on diag blocks ----------------
#define LDA 136
__global__ __launch_bounds__(256) void gram_mfma(
    const unsigned short* __restrict__ poolb, unsigned* __restrict__ simsk,
    float* __restrict__ refl, float* __restrict__ posd) {
    __shared__ short tiles[2 * 128 * LDA];
    short* As = tiles;
    short* Bs = tiles + 128 * LDA;

    int tid = threadIdx.x;
    int bi = blockIdx.x >> 5, bj = blockIdx.x & 31;
    int r0 = bi * 128, c0 = bj * 128;

    const unsigned short* gA = poolb + (size_t)r0 * DD;
    const unsigned short* gB = poolb + (size_t)c0 * DD;
    #pragma unroll
    for (int it = 0; it < 8; it++) {
        int g = it * 256 + tid;
        int row = g >> 4, ch = (g & 15) * 8;
        *(s16x8*)&As[row * LDA + ch] = *(const s16x8*)(gA + row * DD + ch);
        *(s16x8*)&Bs[row * LDA + ch] = *(const s16x8*)(gB + row * DD + ch);
    }
    __syncthreads();

    int l = tid & 63, w = tid >> 6;
    int wr = (w >> 1) * 64, wc = (w & 1) * 64;
    int lr = l & 15, lk = (l >> 4) * 8;

    f32x4 zero = {0.f, 0.f, 0.f, 0.f};
    f32x4 acc[4][4];
    #pragma unroll
    for (int m = 0; m < 4; m++)
        #pragma unroll
        for (int n = 0; n < 4; n++) acc[m][n] = zero;

    #pragma unroll
    for (int kk = 0; kk < 4; kk++) {
        int ko = kk * 32 + lk;
        s16x8 av[4], bv[4];
        #pragma unroll
        for (int m = 0; m < 4; m++)
            av[m] = *(const s16x8*)&As[(wr + m * 16 + lr) * LDA + ko];
        #pragma unroll
        for (int n = 0; n < 4; n++)
            bv[n] = *(const s16x8*)&Bs[(wc + n * 16 + lr) * LDA + ko];
        #pragma unroll
        for (int m = 0; m < 4; m++)
            #pragma unroll
            for (int n = 0; n < 4; n++)
                acc[m][n] = __builtin_amdgcn_mfma_f32_16x16x32_bf16(av[m], bv[n], acc[m][n], 0, 0, 0);
    }

    int fq = (l >> 4) * 4, fr = l & 15;

    #pragma unroll
    for (int m = 0; m < 4; m++)
        #pragma unroll
        for (int n = 0; n < 4; n++) {
            int grow = r0 + wr + m * 16 + fq;
            int gcol = c0 + wc + n * 16 + fr;
            size_t base = (size_t)grow * PP + gcol;
            #pragma unroll
            for (int reg = 0; reg < 4; reg++)
                simsk[base + (size_t)reg * PP] = fkey(acc[m][n][reg]);
        }

    if (r0 == c0 || c0 == (r0 ^ NN)) {
        #pragma unroll
        for (int m = 0; m < 4; m++)
            #pragma unroll
            for (int n = 0; n < 4; n++) {
                int grow = r0 + wr + m * 16 + fq;
                int gcol = c0 + wc + n * 16 + fr;
                #pragma unroll
                for (int reg = 0; reg < 4; reg++) {
                    float v = acc[m][n][reg];
                    if (gcol == grow + reg) refl[gcol] = v;
                    if (gcol == ((grow + reg) ^ NN)) posd[grow + reg] = v;
                }
            }
    }
}

// ---------------- top-204 select + negsum (from inverted keys) ----------------
__global__ __launch_bounds__(256) void rowselect(
    const unsigned* __restrict__ keys, int* __restrict__ topidx,
    float* __restrict__ negsum) {
    __shared__ int hist[4][256];         // per-wave copies
    __shared__ uint2 cand[CAP];
    __shared__ float part[4];
    __shared__ int scal[4];   // 0:B  1:cum  2:P16  3:cnt

    int tid = threadIdx.x, w = tid >> 6, l = tid & 63;
    int r = blockIdx.x;
    const uint4* rp = (const uint4*)(keys + (size_t)r * PP);

    uint4 va[4];
    #pragma unroll
    for (int j = 0; j < 4; j++) va[j] = rp[tid + j * 256];

    // negsum: exp-sum of inverted keys
    float es = 0.f;
    #pragma unroll
    for (int j = 0; j < 4; j++) {
        es += __builtin_exp2f(EXP2C * fkinv(va[j].x))
            + __builtin_exp2f(EXP2C * fkinv(va[j].y))
            + __builtin_exp2f(EXP2C * fkinv(va[j].z))
            + __builtin_exp2f(EXP2C * fkinv(va[j].w));
    }
    #pragma unroll
    for (int mask = 1; mask < 64; mask <<= 1) es += __shfl_xor(es, mask);
    if (l == 0) part[w] = es;

    #pragma unroll
    for (int cpy = 0; cpy < 4; cpy++) hist[cpy][tid] = 0;
    if (tid == 0) scal[3] = 0;
    __syncthreads();
    if (tid == 0) negsum[r] = part[0] + part[1] + part[2] + part[3];

    // hist1 on key[31:24], per-wave copy
    #pragma unroll
    for (int j = 0; j < 4; j++) {
        atomicAdd(&hist[w][va[j].x >> 24], 1);
        atomicAdd(&hist[w][va[j].y >> 24], 1);
        atomicAdd(&hist[w][va[j].z >> 24], 1);
        atomicAdd(&hist[w][va[j].w >> 24], 1);
    }
    __syncthreads();
    if (w == 0) {
        int4 h0 = ((const int4*)hist[0])[l];
        int4 h1 = ((const int4*)hist[1])[l];
        int4 h2 = ((const int4*)hist[2])[l];
        int4 h3 = ((const int4*)hist[3])[l];
        int4 h4 = make_int4(h0.x + h1.x + h2.x + h3.x, h0.y + h1.y + h2.y + h3.y,
                            h0.z + h1.z + h2.z + h3.z, h0.w + h1.w + h2.w + h3.w);
        int s = h4.x + h4.y + h4.z + h4.w;
        int suf = s;
        #pragma unroll
        for (int off = 1; off < 64; off <<= 1) {
            int x = __shfl_down(suf, off);
            if (l + off < 64) suf += x;
        }
        int A = suf - s;
        int ca3 = A, ca2 = A + h4.w, ca1 = ca2 + h4.z, ca0 = ca1 + h4.y;
        if (ca3 < THR && THR <= ca3 + h4.w) { scal[0] = 4 * l + 3; scal[1] = ca3; }
        if (ca2 < THR && THR <= ca2 + h4.z) { scal[0] = 4 * l + 2; scal[1] = ca2; }
        if (ca1 < THR && THR <= ca1 + h4.y) { scal[0] = 4 * l + 1; scal[1] = ca1; }
        if (ca0 < THR && THR <= ca0 + h4.x) { scal[0] = 4 * l + 0; scal[1] = ca0; }
    }
    __syncthreads();
    unsigned B = (unsigned)scal[0];
    int base = scal[1];
    #pragma unroll
    for (int cpy = 0; cpy < 4; cpy++) hist[cpy][tid] = 0;
    __syncthreads();

    // hist2 on key[23:16] within bin B
    #pragma unroll
    for (int j = 0; j < 4; j++) {
        #pragma unroll
        for (int c = 0; c < 4; c++) {
            unsigned key = (c == 0) ? va[j].x : (c == 1) ? va[j].y : (c == 2) ? va[j].z : va[j].w;
            if ((key >> 24) == B) atomicAdd(&hist[w][(key >> 16) & 255], 1);
        }
    }
    __syncthreads();
    if (w == 0) {
        int4 h0 = ((const int4*)hist[0])[l];
        int4 h1 = ((const int4*)hist[1])[l];
        int4 h2 = ((const int4*)hist[2])[l];
        int4 h3 = ((const int4*)hist[3])[l];
        int4 h4 = make_int4(h0.x + h1.x + h2.x + h3.x, h0.y + h1.y + h2.y + h3.y,
                            h0.z + h1.z + h2.z + h3.z, h0.w + h1.w + h2.w + h3.w);
        int s = h4.x + h4.y + h4.z + h4.w;
        int suf = s;
        #pragma unroll
        for (int off = 1; off < 64; off <<= 1) {
            int x = __shfl_down(suf, off);
            if (l + off < 64) suf += x;
        }
        int A = base + suf - s;
        int ca3 = A, ca2 = A + h4.w, ca1 = ca2 + h4.z, ca0 = ca1 + h4.y;
        if (ca3 < THR && THR <= ca3 + h4.w) scal[2] = (int)((B << 8) | (4 * l + 3));
        if (ca2 < THR && THR <= ca2 + h4.z) scal[2] = (int)((B << 8) | (4 * l + 2));
        if (ca1 < THR && THR <= ca1 + h4.y) scal[2] = (int)((B << 8) | (4 * l + 1));
        if (ca0 < THR && THR <= ca0 + h4.x) scal[2] = (int)((B << 8) | (4 * l + 0));
    }
    __syncthreads();
    unsigned P16 = (unsigned)scal[2];

    // collect candidates
    #pragma unroll
    for (int j = 0; j < 4; j++) {
        int col0 = (tid + j * 256) * 4;
        #pragma unroll
        for (int c = 0; c < 4; c++) {
            unsigned key = (c == 0) ? va[j].x : (c == 1) ? va[j].y : (c == 2) ? va[j].z : va[j].w;
            if ((key >> 16) >= P16) {
                int p = atomicAdd(&scal[3], 1);
                if (p < CAP) cand[p] = make_uint2(key, (unsigned)(col0 + c));
            }
        }
    }
    __syncthreads();

    // rank (key desc, col asc)
    int C = min(scal[3], CAP);
    #pragma unroll
    for (int o = 0; o < 2; o++) {
        int t = tid + o * 256;
        if (t < C) {
            uint2 me = cand[t];
            int rk = 0;
            for (int c = 0; c < C; c++) {
                uint2 cd = cand[c];
                rk += (cd.x > me.x || (cd.x == me.x && (int)cd.y < (int)me.y)) ? 1 : 0;
            }
            if (rk < THR) topidx[(size_t)r * THR + rk] = (int)me.y;
        }
    }
}

// ---------------- mixloss: LDS-staged bf16 candidate rows ----------------
__global__ __launch_bounds__(512) void mixloss(
    const unsigned short* __restrict__ Pb, const float* __restrict__ pool_n,
    const float* __restrict__ proj_b,
    const float* __restrict__ negsum, const float* __restrict__ refl,
    const float* __restrict__ posd, const int* __restrict__ topidx,
    const int* __restrict__ idx1, const int* __restrict__ idx2,
    float* __restrict__ out) {
    __shared__ unsigned short pbs[THR][136];   // 55.5 KB, 272B stride
    __shared__ int top_sh[THR];
    __shared__ int idx_sh[2 * SS];
    __shared__ float pn2[SS * 17];             // 10.2 KB
    __shared__ float pdt[SS * 17];
    __shared__ float red2[8];

    int tid = threadIdx.x, w = tid >> 6, l = tid & 63;
    int r = blockIdx.x;
    int i = r & (NN - 1);
    const int* idxp = ((r >= NN) ? idx2 : idx1) + (size_t)i * (2 * SS);

    if (tid < THR) top_sh[tid] = topidx[(size_t)r * THR + tid];
    if (tid < 2 * SS) idx_sh[tid] = idxp[tid];
    __syncthreads();

    // stage 204 bf16 rows (16B chunks, fully parallel)
    for (int e = tid; e < THR * 16; e += 512) {
        int j = e >> 4, ch = (e & 15) * 8;
        *(s16x8*)&pbs[j][ch] = *(const s16x8*)(Pb + (size_t)top_sh[j] * DD + ch);
    }

    int gid = tid >> 4, sub = tid & 15, d0 = sub * 8;
    float qv[8], bv[8];
    *(float4*)&qv[0] = *(const float4*)(pool_n + (size_t)r * DD + d0);
    *(float4*)&qv[4] = *(const float4*)(pool_n + (size_t)r * DD + d0 + 4);
    *(float4*)&bv[0] = *(const float4*)(proj_b + d0);
    *(float4*)&bv[4] = *(const float4*)(proj_b + d0 + 4);
    __syncthreads();

    // phase 1: per-lane partials from LDS rows
    for (int p = gid; p < 75; p += 32) {
        int t = 2 * p;
        s16x8 x1 = *(const s16x8*)&pbs[idx_sh[t]][d0];
        s16x8 y1 = *(const s16x8*)&pbs[idx_sh[t + SS]][d0];
        s16x8 x2 = *(const s16x8*)&pbs[idx_sh[t + 1]][d0];
        s16x8 y2 = *(const s16x8*)&pbs[idx_sh[t + 1 + SS]][d0];
        float n2a = 0.f, dta = 0.f, n2b = 0.f, dtb = 0.f;
        #pragma unroll
        for (int k = 0; k < 8; k++) {
            float ha = fmaf(0.2f, bf2f((unsigned short)x1[k]),
                       fmaf(0.8f, bf2f((unsigned short)y1[k]), bv[k]));
            float hb = fmaf(0.2f, bf2f((unsigned short)x2[k]),
                       fmaf(0.8f, bf2f((unsigned short)y2[k]), bv[k]));
            n2a = fmaf(ha, ha, n2a);
            dta = fmaf(ha, qv[k], dta);
            n2b = fmaf(hb, hb, n2b);
            dtb = fmaf(hb, qv[k], dtb);
        }
        pn2[t * 17 + sub] = n2a;
        pdt[t * 17 + sub] = dta;
        pn2[(t + 1) * 17 + sub] = n2b;
        pdt[(t + 1) * 17 + sub] = dtb;
    }
    __syncthreads();

    // phase 2: thread t reduces its 16 partials
    float wsum = 0.f;
    if (tid < SS) {
        float n2 = 0.f, dt = 0.f;
        #pragma unroll
        for (int k = 0; k < 16; k++) {
            n2 += pn2[tid * 17 + k];
            dt += pdt[tid * 17 + k];
        }
        wsum = __builtin_exp2f(EXP2C * dt * rsqrtf(fmaxf(n2, 1e-24f)));
    }
    #pragma unroll
    for (int mask = 1; mask < 64; mask <<= 1) wsum += __shfl_xor(wsum, mask);
    if (l == 0) red2[w] = wsum;
    __syncthreads();
    if (tid == 0) {
        float negm = red2[0] + red2[1] + red2[2] + red2[3]
                   + red2[4] + red2[5] + red2[6] + red2[7];
        float den = negsum[r] + negm - refl[r];
        float loss = logf(den) - 2.0f * posd[r];
        atomicAdd(out, loss * (1.0f / 4096.0f));
    }
}

extern "C" void kernel_launch(void* const* d_in, const int* in_sizes, int n_in,
                              void* d_out, int out_size, void* d_ws, size_t ws_size,
                              hipStream_t stream) {
    const float* z1  = (const float*)d_in[0];
    const float* z2  = (const float*)d_in[1];
    const float* pw  = (const float*)d_in[2];
    const float* pb  = (const float*)d_in[3];
    const int* idx1  = (const int*)d_in[4];
    const int* idx2  = (const int*)d_in[5];
    float* out = (float*)d_out;

    float* wsf = (float*)d_ws;
    float* pool_n  = wsf + OFF_POOLN;
    float* wtT     = wsf + OFF_WTT;
    unsigned short* Pb = (unsigned short*)(wsf + OFF_PB);
    float* negs    = wsf + OFF_NEG;
    float* rfl     = wsf + OFF_REFL;
    float* psd     = wsf + OFF_POSD;
    int*   topi    = (int*)(wsf + OFF_TOPI);
    unsigned short* poolb = (unsigned short*)(wsf + OFF_POOLB);
    unsigned* simsk = (unsigned*)(wsf + OFF_SIMS);

    hipMemsetAsync(d_out, 0, sizeof(float), stream);

    prep_norm<<<PP, 64, 0, stream>>>(z1, z2, pool_n, poolb);
    prep_wt<<<64, 256, 0, stream>>>(pw, wtT);
    prep_proj<<<PP / 8, 256, 0, stream>>>(z1, z2, wtT, Pb);
    gram_mfma<<<1024, 256, 0, stream>>>(poolb, simsk, rfl, psd);
    rowselect<<<PP, 256, 0, stream>>>(simsk, topi, negs);
    mixloss<<<PP, 512, 0, stream>>>(Pb, pool_n, pb, negs, rfl, psd, topi,
                                    idx1, idx2, out);
}

// Round 11
// 148.838 us; speedup vs baseline: 1.1330x; 1.0039x over previous
//
#include <hip/hip_runtime.h>
#include <math.h>

#define NN 2048
#define PP 4096
#define DD 128
#define SS 150
#define THR 204
#define CAP 512
#define EXP2C 2.8853900817779268f   // 2/ln(2): exp(2x) = 2^(EXP2C*x)

typedef float f32x4 __attribute__((ext_vector_type(4)));
typedef short s16x8 __attribute__((ext_vector_type(8)));

// ws layout (float offsets) — bf16 arrays are 4096*128 u16 = 262144 floats each
#define OFF_POOLN 0          // 524288 f32
#define OFF_WTT   524288     // 16384 f32
#define OFF_PB    540672     // 262144 floats (bf16 projected pool)
#define OFF_NEG   802816     // 4096
#define OFF_REFL  806912     // 4096
#define OFF_POSD  811008     // 4096
#define OFF_TOPI  815104     // 835584 ints
#define OFF_POOLB 1650688    // 262144 floats (bf16 normalized pool)
#define OFF_SIMS  1912832    // 4096*4096 u32 keys = 64 MB

__device__ __forceinline__ unsigned fkey(float v) {
    unsigned u = __float_as_uint(v);
    return u ^ (unsigned)(((int)u >> 31) | 0x80000000);
}
__device__ __forceinline__ float fkinv(unsigned k) {
    unsigned u = (k & 0x80000000u) ? (k ^ 0x80000000u) : ~k;
    return __uint_as_float(u);
}
__device__ __forceinline__ unsigned short f2bf(float f) {
    unsigned u = __float_as_uint(f);
    u = (u + 0x7FFFu + ((u >> 16) & 1u)) >> 16;
    return (unsigned short)u;
}
__device__ __forceinline__ float bf2f(unsigned short h) {
    return __uint_as_float((unsigned)h << 16);
}

// ---------------- prep: normalize pool rows -> f32 + bf16 ----------------
__global__ void prep_norm(const float* __restrict__ z1, const float* __restrict__ z2,
                          float* __restrict__ pool_n, unsigned short* __restrict__ poolb) {
    int b = blockIdx.x;
    int l = threadIdx.x;
    const float* src = (b < NN) ? z1 + (size_t)b * DD : z2 + (size_t)(b - NN) * DD;
    float2 v = *(const float2*)(src + 2 * l);
    float ss = v.x * v.x + v.y * v.y;
    #pragma unroll
    for (int mask = 1; mask < 64; mask <<= 1) ss += __shfl_xor(ss, mask);
    float inv = 1.0f / fmaxf(sqrtf(ss), 1e-12f);
    float2 nv; nv.x = v.x * inv; nv.y = v.y * inv;
    *(float2*)(pool_n + (size_t)b * DD + 2 * l) = nv;
    ((unsigned*)poolb)[(size_t)b * 64 + l] =
        (unsigned)f2bf(nv.x) | ((unsigned)f2bf(nv.y) << 16);
}

// ---------------- prep: transpose proj_w (fp32), layout [k][d] ----------------
__global__ void prep_wt(const float* __restrict__ pw, float* __restrict__ wtT) {
    int e = blockIdx.x * 256 + threadIdx.x;
    int k = e >> 7, d = e & 127;
    wtT[e] = pw[d * DD + k];
}

// ---------------- prep: Pb = bf16(z_pool @ W^T) ----------------
__global__ __launch_bounds__(256, 4) void prep_proj(
    const float* __restrict__ z1, const float* __restrict__ z2,
    const float* __restrict__ wtT, unsigned short* __restrict__ Pb) {
    __shared__ float z_sh[8][DD];
    int tid = threadIdx.x;
    int r0 = blockIdx.x * 8;
    for (int e = tid; e < 8 * DD; e += 256) {
        int rr = r0 + (e >> 7);
        z_sh[e >> 7][e & 127] = (rr < NN) ? z1[(size_t)rr * DD + (e & 127)]
                                          : z2[(size_t)(rr - NN) * DD + (e & 127)];
    }
    __syncthreads();
    int d = tid & 127, h = tid >> 7;
    float a0 = 0.f, a1 = 0.f, a2 = 0.f, a3 = 0.f;
    for (int k = 0; k < DD; k++) {
        float wv = wtT[k * DD + d];
        a0 += z_sh[4 * h + 0][k] * wv;
        a1 += z_sh[4 * h + 1][k] * wv;
        a2 += z_sh[4 * h + 2][k] * wv;
        a3 += z_sh[4 * h + 3][k] * wv;
    }
    Pb[(size_t)(r0 + 4 * h + 0) * DD + d] = f2bf(a0);
    Pb[(size_t)(r0 + 4 * h + 1) * DD + d] = f2bf(a1);
    Pb[(size_t)(r0 + 4 * h + 2) * DD + d] = f2bf(a2);
    Pb[(size_t)(r0 + 4 * h + 3) * DD + d] = f2bf(a3);
}

// ---------------- MFMA gram -> order-preserving keys; refl/posd on diag blocks ----------------
#define LDA 136
__global__ __launch_bounds__(256) void gram_mfma(
    const unsigned short* __restrict__ poolb, unsigned* __restrict__ simsk,
    float* __restrict__ refl, float* __restrict__ posd) {
    __shared__ short tiles[2 * 128 * LDA];
    short* As = tiles;
    short* Bs = tiles + 128 * LDA;

    int tid = threadIdx.x;
    int bi = blockIdx.x >> 5, bj = blockIdx.x & 31;
    int r0 = bi * 128, c0 = bj * 128;

    const unsigned short* gA = poolb + (size_t)r0 * DD;
    const unsigned short* gB = poolb + (size_t)c0 * DD;
    #pragma unroll
    for (int it = 0; it < 8; it++) {
        int g = it * 256 + tid;
        int row = g >> 4, ch = (g & 15) * 8;
        *(s16x8*)&As[row * LDA + ch] = *(const s16x8*)(gA + row * DD + ch);
        *(s16x8*)&Bs[row * LDA + ch] = *(const s16x8*)(gB + row * DD + ch);
    }
    __syncthreads();

    int l = tid & 63, w = tid >> 6;
    int wr = (w >> 1) * 64, wc = (w & 1) * 64;
    int lr = l & 15, lk = (l >> 4) * 8;

    f32x4 zero = {0.f, 0.f, 0.f, 0.f};
    f32x4 acc[4][4];
    #pragma unroll
    for (int m = 0; m < 4; m++)
        #pragma unroll
        for (int n = 0; n < 4; n++) acc[m][n] = zero;

    #pragma unroll
    for (int kk = 0; kk < 4; kk++) {
        int ko = kk * 32 + lk;
        s16x8 av[4], bv[4];
        #pragma unroll
        for (int m = 0; m < 4; m++)
            av[m] = *(const s16x8*)&As[(wr + m * 16 + lr) * LDA + ko];
        #pragma unroll
        for (int n = 0; n < 4; n++)
            bv[n] = *(const s16x8*)&Bs[(wc + n * 16 + lr) * LDA + ko];
        #pragma unroll
        for (int m = 0; m < 4; m++)
            #pragma unroll
            for (int n = 0; n < 4; n++)
                acc[m][n] = __builtin_amdgcn_mfma_f32_16x16x32_bf16(av[m], bv[n], acc[m][n], 0, 0, 0);
    }

    int fq = (l >> 4) * 4, fr = l & 15;

    #pragma unroll
    for (int m = 0; m < 4; m++)
        #pragma unroll
        for (int n = 0; n < 4; n++) {
            int grow = r0 + wr + m * 16 + fq;
            int gcol = c0 + wc + n * 16 + fr;
            size_t base = (size_t)grow * PP + gcol;
            #pragma unroll
            for (int reg = 0; reg < 4; reg++)
                simsk[base + (size_t)reg * PP] = fkey(acc[m][n][reg]);
        }

    if (r0 == c0 || c0 == (r0 ^ NN)) {
        #pragma unroll
        for (int m = 0; m < 4; m++)
            #pragma unroll
            for (int n = 0; n < 4; n++) {
                int grow = r0 + wr + m * 16 + fq;
                int gcol = c0 + wc + n * 16 + fr;
                #pragma unroll
                for (int reg = 0; reg < 4; reg++) {
                    float v = acc[m][n][reg];
                    if (gcol == grow + reg) refl[gcol] = v;
                    if (gcol == ((grow + reg) ^ NN)) posd[grow + reg] = v;
                }
            }
    }
}

// ---------------- top-204 select + negsum (from inverted keys) ----------------
__global__ __launch_bounds__(256) void rowselect(
    const unsigned* __restrict__ keys, int* __restrict__ topidx,
    float* __restrict__ negsum) {
    __shared__ int hist[8][256];         // per-half-wave copies
    __shared__ uint2 cand[CAP];
    __shared__ float part[4];
    __shared__ int scal[4];   // 0:B  1:cum  2:P16  3:cnt

    int tid = threadIdx.x, w = tid >> 6, l = tid & 63;
    int hs = tid >> 5;
    int r = blockIdx.x;
    const uint4* rp = (const uint4*)(keys + (size_t)r * PP);

    uint4 va[4];
    #pragma unroll
    for (int j = 0; j < 4; j++) va[j] = rp[tid + j * 256];

    // negsum: exp-sum of inverted keys
    float es = 0.f;
    #pragma unroll
    for (int j = 0; j < 4; j++) {
        es += __builtin_exp2f(EXP2C * fkinv(va[j].x))
            + __builtin_exp2f(EXP2C * fkinv(va[j].y))
            + __builtin_exp2f(EXP2C * fkinv(va[j].z))
            + __builtin_exp2f(EXP2C * fkinv(va[j].w));
    }
    #pragma unroll
    for (int mask = 1; mask < 64; mask <<= 1) es += __shfl_xor(es, mask);
    if (l == 0) part[w] = es;

    #pragma unroll
    for (int cpy = 0; cpy < 8; cpy++) hist[cpy][tid] = 0;
    if (tid == 0) scal[3] = 0;
    __syncthreads();
    if (tid == 0) negsum[r] = part[0] + part[1] + part[2] + part[3];

    // hist1 on key[31:24], per-half-wave copy
    #pragma unroll
    for (int j = 0; j < 4; j++) {
        atomicAdd(&hist[hs][va[j].x >> 24], 1);
        atomicAdd(&hist[hs][va[j].y >> 24], 1);
        atomicAdd(&hist[hs][va[j].z >> 24], 1);
        atomicAdd(&hist[hs][va[j].w >> 24], 1);
    }
    __syncthreads();
    if (w == 0) {
        int4 h4 = make_int4(0, 0, 0, 0);
        #pragma unroll
        for (int cpy = 0; cpy < 8; cpy++) {
            int4 h = ((const int4*)hist[cpy])[l];
            h4.x += h.x; h4.y += h.y; h4.z += h.z; h4.w += h.w;
        }
        int s = h4.x + h4.y + h4.z + h4.w;
        int suf = s;
        #pragma unroll
        for (int off = 1; off < 64; off <<= 1) {
            int x = __shfl_down(suf, off);
            if (l + off < 64) suf += x;
        }
        int A = suf - s;
        int ca3 = A, ca2 = A + h4.w, ca1 = ca2 + h4.z, ca0 = ca1 + h4.y;
        if (ca3 < THR && THR <= ca3 + h4.w) { scal[0] = 4 * l + 3; scal[1] = ca3; }
        if (ca2 < THR && THR <= ca2 + h4.z) { scal[0] = 4 * l + 2; scal[1] = ca2; }
        if (ca1 < THR && THR <= ca1 + h4.y) { scal[0] = 4 * l + 1; scal[1] = ca1; }
        if (ca0 < THR && THR <= ca0 + h4.x) { scal[0] = 4 * l + 0; scal[1] = ca0; }
    }
    __syncthreads();
    unsigned B = (unsigned)scal[0];
    int base = scal[1];
    #pragma unroll
    for (int cpy = 0; cpy < 8; cpy++) hist[cpy][tid] = 0;
    __syncthreads();

    // hist2 on key[23:16] within bin B
    #pragma unroll
    for (int j = 0; j < 4; j++) {
        #pragma unroll
        for (int c = 0; c < 4; c++) {
            unsigned key = (c == 0) ? va[j].x : (c == 1) ? va[j].y : (c == 2) ? va[j].z : va[j].w;
            if ((key >> 24) == B) atomicAdd(&hist[hs][(key >> 16) & 255], 1);
        }
    }
    __syncthreads();
    if (w == 0) {
        int4 h4 = make_int4(0, 0, 0, 0);
        #pragma unroll
        for (int cpy = 0; cpy < 8; cpy++) {
            int4 h = ((const int4*)hist[cpy])[l];
            h4.x += h.x; h4.y += h.y; h4.z += h.z; h4.w += h.w;
        }
        int s = h4.x + h4.y + h4.z + h4.w;
        int suf = s;
        #pragma unroll
        for (int off = 1; off < 64; off <<= 1) {
            int x = __shfl_down(suf, off);
            if (l + off < 64) suf += x;
        }
        int A = base + suf - s;
        int ca3 = A, ca2 = A + h4.w, ca1 = ca2 + h4.z, ca0 = ca1 + h4.y;
        if (ca3 < THR && THR <= ca3 + h4.w) scal[2] = (int)((B << 8) | (4 * l + 3));
        if (ca2 < THR && THR <= ca2 + h4.z) scal[2] = (int)((B << 8) | (4 * l + 2));
        if (ca1 < THR && THR <= ca1 + h4.y) scal[2] = (int)((B << 8) | (4 * l + 1));
        if (ca0 < THR && THR <= ca0 + h4.x) scal[2] = (int)((B << 8) | (4 * l + 0));
    }
    __syncthreads();
    unsigned P16 = (unsigned)scal[2];

    // collect candidates
    #pragma unroll
    for (int j = 0; j < 4; j++) {
        int col0 = (tid + j * 256) * 4;
        #pragma unroll
        for (int c = 0; c < 4; c++) {
            unsigned key = (c == 0) ? va[j].x : (c == 1) ? va[j].y : (c == 2) ? va[j].z : va[j].w;
            if ((key >> 16) >= P16) {
                int p = atomicAdd(&scal[3], 1);
                if (p < CAP) cand[p] = make_uint2(key, (unsigned)(col0 + c));
            }
        }
    }
    __syncthreads();

    // rank (key desc, col asc)
    int C = min(scal[3], CAP);
    #pragma unroll
    for (int o = 0; o < 2; o++) {
        int t = tid + o * 256;
        if (t < C) {
            uint2 me = cand[t];
            int rk = 0;
            for (int c = 0; c < C; c++) {
                uint2 cd = cand[c];
                rk += (cd.x > me.x || (cd.x == me.x && (int)cd.y < (int)me.y)) ? 1 : 0;
            }
            if (rk < THR) topidx[(size_t)r * THR + rk] = (int)me.y;
        }
    }
}

// ---------------- mixloss: direct bf16 gathers (Pb is L2-resident), high occupancy ----------------
__global__ __launch_bounds__(512) void mixloss(
    const unsigned short* __restrict__ Pb, const float* __restrict__ pool_n,
    const float* __restrict__ proj_b,
    const float* __restrict__ negsum, const float* __restrict__ refl,
    const float* __restrict__ posd, const int* __restrict__ topidx,
    const int* __restrict__ idx1, const int* __restrict__ idx2,
    float* __restrict__ out) {
    __shared__ int top_sh[THR];
    __shared__ int idx_sh[2 * SS];
    __shared__ float pn2[SS * 17];             // 10.2 KB
    __shared__ float pdt[SS * 17];             // 10.2 KB
    __shared__ float red2[8];

    int tid = threadIdx.x, w = tid >> 6, l = tid & 63;
    int r = blockIdx.x;
    int i = r & (NN - 1);
    const int* idxp = ((r >= NN) ? idx2 : idx1) + (size_t)i * (2 * SS);

    if (tid < THR) top_sh[tid] = topidx[(size_t)r * THR + tid];
    if (tid < 2 * SS) idx_sh[tid] = idxp[tid];

    int gid = tid >> 4, sub = tid & 15, d0 = sub * 8;
    float qv[8], bv[8];
    *(float4*)&qv[0] = *(const float4*)(pool_n + (size_t)r * DD + d0);
    *(float4*)&qv[4] = *(const float4*)(pool_n + (size_t)r * DD + d0 + 4);
    *(float4*)&bv[0] = *(const float4*)(proj_b + d0);
    *(float4*)&bv[4] = *(const float4*)(proj_b + d0 + 4);
    __syncthreads();

    // phase 1: per-lane partials; 32 groups of 16 lanes, t = gid, gid+32, ...
    for (int t = gid; t < SS; t += 32) {
        const unsigned short* p1 = Pb + (size_t)top_sh[idx_sh[t]] * DD + d0;
        const unsigned short* p2 = Pb + (size_t)top_sh[idx_sh[t + SS]] * DD + d0;
        s16x8 x1 = *(const s16x8*)p1;
        s16x8 y1 = *(const s16x8*)p2;
        float n2 = 0.f, dt = 0.f;
        #pragma unroll
        for (int k = 0; k < 8; k++) {
            float h = fmaf(0.2f, bf2f((unsigned short)x1[k]),
                      fmaf(0.8f, bf2f((unsigned short)y1[k]), bv[k]));
            n2 = fmaf(h, h, n2);
            dt = fmaf(h, qv[k], dt);
        }
        pn2[t * 17 + sub] = n2;
        pdt[t * 17 + sub] = dt;
    }
    __syncthreads();

    // phase 2: thread t reduces its 16 partials
    float wsum = 0.f;
    if (tid < SS) {
        float n2 = 0.f, dt = 0.f;
        #pragma unroll
        for (int k = 0; k < 16; k++) {
            n2 += pn2[tid * 17 + k];
            dt += pdt[tid * 17 + k];
        }
        wsum = __builtin_exp2f(EXP2C * dt * rsqrtf(fmaxf(n2, 1e-24f)));
    }
    #pragma unroll
    for (int mask = 1; mask < 64; mask <<= 1) wsum += __shfl_xor(wsum, mask);
    if (l == 0) red2[w] = wsum;
    __syncthreads();
    if (tid == 0) {
        float negm = red2[0] + red2[1] + red2[2] + red2[3]
                   + red2[4] + red2[5] + red2[6] + red2[7];
        float den = negsum[r] + negm - refl[r];
        float loss = logf(den) - 2.0f * posd[r];
        atomicAdd(out, loss * (1.0f / 4096.0f));
    }
}

extern "C" void kernel_launch(void* const* d_in, const int* in_sizes, int n_in,
                              void* d_out, int out_size, void* d_ws, size_t ws_size,
                              hipStream_t stream) {
    const float* z1  = (const float*)d_in[0];
    const float* z2  = (const float*)d_in[1];
    const float* pw  = (const float*)d_in[2];
    const float* pb  = (const float*)d_in[3];
    const int* idx1  = (const int*)d_in[4];
    const int* idx2  = (const int*)d_in[5];
    float* out = (float*)d_out;

    float* wsf = (float*)d_ws;
    float* pool_n  = wsf + OFF_POOLN;
    float* wtT     = wsf + OFF_WTT;
    unsigned short* Pb = (unsigned short*)(wsf + OFF_PB);
    float* negs    = wsf + OFF_NEG;
    float* rfl     = wsf + OFF_REFL;
    float* psd     = wsf + OFF_POSD;
    int*   topi    = (int*)(wsf + OFF_TOPI);
    unsigned short* poolb = (unsigned short*)(wsf + OFF_POOLB);
    unsigned* simsk = (unsigned*)(wsf + OFF_SIMS);

    hipMemsetAsync(d_out, 0, sizeof(float), stream);

    prep_norm<<<PP, 64, 0, stream>>>(z1, z2, pool_n, poolb);
    prep_wt<<<64, 256, 0, stream>>>(pw, wtT);
    prep_proj<<<PP / 8, 256, 0, stream>>>(z1, z2, wtT, Pb);
    gram_mfma<<<1024, 256, 0, stream>>>(poolb, simsk, rfl, psd);
    rowselect<<<PP, 256, 0, stream>>>(simsk, topi, negs);
    mixloss<<<PP, 512, 0, stream>>>(Pb, pool_n, pb, negs, rfl, psd, topi,
                                    idx1, idx2, out);
}

// Round 12
// 138.392 us; speedup vs baseline: 1.2185x; 1.0755x over previous
//
#include <hip/hip_runtime.h>
#include <math.h>

#define NN 2048
#define PP 4096
#define DD 128
#define SS 150
#define THR 204
#define CAP 512
#define EXP2C 2.8853900817779268f   // 2/ln(2): exp(2x) = 2^(EXP2C*x)

typedef float f32x4 __attribute__((ext_vector_type(4)));
typedef short s16x8 __attribute__((ext_vector_type(8)));

// ws layout (float offsets) — bf16 arrays are 4096*128 u16 = 262144 floats each
#define OFF_POOLN 0          // 524288 f32
#define OFF_WTT   524288     // 16384 f32
#define OFF_PB    540672     // 262144 floats (bf16 projected pool)
#define OFF_NEG   802816     // 4096
#define OFF_REFL  806912     // 4096
#define OFF_POSD  811008     // 4096
#define OFF_TOPI  815104     // 835584 ints
#define OFF_POOLB 1650688    // 262144 floats (bf16 normalized pool)
#define OFF_SIMS  1912832    // 4096*4096 f32 = 64 MB

__device__ __forceinline__ unsigned fkey(float v) {
    unsigned u = __float_as_uint(v);
    return u ^ (unsigned)(((int)u >> 31) | 0x80000000);
}
__device__ __forceinline__ unsigned short f2bf(float f) {
    unsigned u = __float_as_uint(f);
    u = (u + 0x7FFFu + ((u >> 16) & 1u)) >> 16;
    return (unsigned short)u;
}
__device__ __forceinline__ float bf2f(unsigned short h) {
    return __uint_as_float((unsigned)h << 16);
}
// value-linear monotone bin over [-1,1]: identical expression everywhere
__device__ __forceinline__ int binOf(float v) {
    int b = (int)fmaf(v, 512.f, 512.f);
    return min(max(b, 0), 1023);
}

// ---------------- prep: normalize pool rows -> f32 + bf16 ----------------
__global__ void prep_norm(const float* __restrict__ z1, const float* __restrict__ z2,
                          float* __restrict__ pool_n, unsigned short* __restrict__ poolb) {
    int b = blockIdx.x;
    int l = threadIdx.x;
    const float* src = (b < NN) ? z1 + (size_t)b * DD : z2 + (size_t)(b - NN) * DD;
    float2 v = *(const float2*)(src + 2 * l);
    float ss = v.x * v.x + v.y * v.y;
    #pragma unroll
    for (int mask = 1; mask < 64; mask <<= 1) ss += __shfl_xor(ss, mask);
    float inv = 1.0f / fmaxf(sqrtf(ss), 1e-12f);
    float2 nv; nv.x = v.x * inv; nv.y = v.y * inv;
    *(float2*)(pool_n + (size_t)b * DD + 2 * l) = nv;
    ((unsigned*)poolb)[(size_t)b * 64 + l] =
        (unsigned)f2bf(nv.x) | ((unsigned)f2bf(nv.y) << 16);
}

// ---------------- prep: transpose proj_w (fp32), layout [k][d] ----------------
__global__ void prep_wt(const float* __restrict__ pw, float* __restrict__ wtT) {
    int e = blockIdx.x * 256 + threadIdx.x;
    int k = e >> 7, d = e & 127;
    wtT[e] = pw[d * DD + k];
}

// ---------------- prep: Pb = bf16(z_pool @ W^T) ----------------
__global__ __launch_bounds__(256, 4) void prep_proj(
    const float* __restrict__ z1, const float* __restrict__ z2,
    const float* __restrict__ wtT, unsigned short* __restrict__ Pb) {
    __shared__ float z_sh[8][DD];
    int tid = threadIdx.x;
    int r0 = blockIdx.x * 8;
    for (int e = tid; e < 8 * DD; e += 256) {
        int rr = r0 + (e >> 7);
        z_sh[e >> 7][e & 127] = (rr < NN) ? z1[(size_t)rr * DD + (e & 127)]
                                          : z2[(size_t)(rr - NN) * DD + (e & 127)];
    }
    __syncthreads();
    int d = tid & 127, h = tid >> 7;
    float a0 = 0.f, a1 = 0.f, a2 = 0.f, a3 = 0.f;
    for (int k = 0; k < DD; k++) {
        float wv = wtT[k * DD + d];
        a0 += z_sh[4 * h + 0][k] * wv;
        a1 += z_sh[4 * h + 1][k] * wv;
        a2 += z_sh[4 * h + 2][k] * wv;
        a3 += z_sh[4 * h + 3][k] * wv;
    }
    Pb[(size_t)(r0 + 4 * h + 0) * DD + d] = f2bf(a0);
    Pb[(size_t)(r0 + 4 * h + 1) * DD + d] = f2bf(a1);
    Pb[(size_t)(r0 + 4 * h + 2) * DD + d] = f2bf(a2);
    Pb[(size_t)(r0 + 4 * h + 3) * DD + d] = f2bf(a3);
}

// ---------------- MFMA gram -> f32 sims; refl/posd on diag blocks ----------------
#define LDA 136
__global__ __launch_bounds__(256) void gram_mfma(
    const unsigned short* __restrict__ poolb, float* __restrict__ sims,
    float* __restrict__ refl, float* __restrict__ posd) {
    __shared__ short tiles[2 * 128 * LDA];
    short* As = tiles;
    short* Bs = tiles + 128 * LDA;

    int tid = threadIdx.x;
    int bi = blockIdx.x >> 5, bj = blockIdx.x & 31;
    int r0 = bi * 128, c0 = bj * 128;

    const unsigned short* gA = poolb + (size_t)r0 * DD;
    const unsigned short* gB = poolb + (size_t)c0 * DD;
    #pragma unroll
    for (int it = 0; it < 8; it++) {
        int g = it * 256 + tid;
        int row = g >> 4, ch = (g & 15) * 8;
        *(s16x8*)&As[row * LDA + ch] = *(const s16x8*)(gA + row * DD + ch);
        *(s16x8*)&Bs[row * LDA + ch] = *(const s16x8*)(gB + row * DD + ch);
    }
    __syncthreads();

    int l = tid & 63, w = tid >> 6;
    int wr = (w >> 1) * 64, wc = (w & 1) * 64;
    int lr = l & 15, lk = (l >> 4) * 8;

    f32x4 zero = {0.f, 0.f, 0.f, 0.f};
    f32x4 acc[4][4];
    #pragma unroll
    for (int m = 0; m < 4; m++)
        #pragma unroll
        for (int n = 0; n < 4; n++) acc[m][n] = zero;

    #pragma unroll
    for (int kk = 0; kk < 4; kk++) {
        int ko = kk * 32 + lk;
        s16x8 av[4], bv[4];
        #pragma unroll
        for (int m = 0; m < 4; m++)
            av[m] = *(const s16x8*)&As[(wr + m * 16 + lr) * LDA + ko];
        #pragma unroll
        for (int n = 0; n < 4; n++)
            bv[n] = *(const s16x8*)&Bs[(wc + n * 16 + lr) * LDA + ko];
        #pragma unroll
        for (int m = 0; m < 4; m++)
            #pragma unroll
            for (int n = 0; n < 4; n++)
                acc[m][n] = __builtin_amdgcn_mfma_f32_16x16x32_bf16(av[m], bv[n], acc[m][n], 0, 0, 0);
    }

    int fq = (l >> 4) * 4, fr = l & 15;

    #pragma unroll
    for (int m = 0; m < 4; m++)
        #pragma unroll
        for (int n = 0; n < 4; n++) {
            int grow = r0 + wr + m * 16 + fq;
            int gcol = c0 + wc + n * 16 + fr;
            size_t base = (size_t)grow * PP + gcol;
            #pragma unroll
            for (int reg = 0; reg < 4; reg++)
                sims[base + (size_t)reg * PP] = acc[m][n][reg];
        }

    if (r0 == c0 || c0 == (r0 ^ NN)) {
        #pragma unroll
        for (int m = 0; m < 4; m++)
            #pragma unroll
            for (int n = 0; n < 4; n++) {
                int grow = r0 + wr + m * 16 + fq;
                int gcol = c0 + wc + n * 16 + fr;
                #pragma unroll
                for (int reg = 0; reg < 4; reg++) {
                    float v = acc[m][n][reg];
                    if (gcol == grow + reg) refl[gcol] = v;
                    if (gcol == ((grow + reg) ^ NN)) posd[grow + reg] = v;
                }
            }
    }
}

// ---------------- top-204 select + negsum; single 1024-bin value-linear hist ----------------
__global__ __launch_bounds__(256) void rowselect(
    const float* __restrict__ sims, int* __restrict__ topidx,
    float* __restrict__ negsum) {
    __shared__ int hist[2][1024];        // 8 KB, 2 copies (tid>>7)
    __shared__ uint2 cand[CAP];
    __shared__ float part[4];
    __shared__ int scal[2];              // 0:bin  1:cnt

    int tid = threadIdx.x, w = tid >> 6, l = tid & 63;
    int hs = tid >> 7;
    int r = blockIdx.x;
    const float4* rp = (const float4*)(sims + (size_t)r * PP);

    float4 va[4];
    #pragma unroll
    for (int j = 0; j < 4; j++) va[j] = rp[tid + j * 256];

    // negsum: exp-sum of full row
    float es = 0.f;
    #pragma unroll
    for (int j = 0; j < 4; j++) {
        es += __builtin_exp2f(EXP2C * va[j].x) + __builtin_exp2f(EXP2C * va[j].y)
            + __builtin_exp2f(EXP2C * va[j].z) + __builtin_exp2f(EXP2C * va[j].w);
    }
    #pragma unroll
    for (int mask = 1; mask < 64; mask <<= 1) es += __shfl_xor(es, mask);
    if (l == 0) part[w] = es;

    #pragma unroll
    for (int q = 0; q < 4; q++) hist[0][tid + q * 256] = 0;
    #pragma unroll
    for (int q = 0; q < 4; q++) hist[1][tid + q * 256] = 0;
    if (tid == 0) scal[1] = 0;
    __syncthreads();
    if (tid == 0) negsum[r] = part[0] + part[1] + part[2] + part[3];

    // one hist pass on value-linear bins
    #pragma unroll
    for (int j = 0; j < 4; j++) {
        atomicAdd(&hist[hs][binOf(va[j].x)], 1);
        atomicAdd(&hist[hs][binOf(va[j].y)], 1);
        atomicAdd(&hist[hs][binOf(va[j].z)], 1);
        atomicAdd(&hist[hs][binOf(va[j].w)], 1);
    }
    __syncthreads();

    // scan: wave 0; lane l owns bins [l*16, l*16+16)
    if (w == 0) {
        int b16[16];
        int s = 0;
        #pragma unroll
        for (int q = 0; q < 4; q++) {
            int4 h0 = ((const int4*)hist[0])[l * 4 + q];
            int4 h1 = ((const int4*)hist[1])[l * 4 + q];
            b16[q * 4 + 0] = h0.x + h1.x; b16[q * 4 + 1] = h0.y + h1.y;
            b16[q * 4 + 2] = h0.z + h1.z; b16[q * 4 + 3] = h0.w + h1.w;
            s += b16[q * 4] + b16[q * 4 + 1] + b16[q * 4 + 2] + b16[q * 4 + 3];
        }
        int suf = s;
        #pragma unroll
        for (int off = 1; off < 64; off <<= 1) {
            int x = __shfl_down(suf, off);
            if (l + off < 64) suf += x;
        }
        int cum = suf - s;                 // strictly above this lane's bins
        #pragma unroll
        for (int j = 15; j >= 0; j--) {
            if (cum < THR && THR <= cum + b16[j]) scal[0] = l * 16 + j;
            cum += b16[j];
        }
    }
    __syncthreads();
    int bthr = scal[0];

    // collect candidates: bin >= bthr (identical binOf expression -> consistent)
    #pragma unroll
    for (int j = 0; j < 4; j++) {
        int col0 = (tid + j * 256) * 4;
        #pragma unroll
        for (int c = 0; c < 4; c++) {
            float v = (c == 0) ? va[j].x : (c == 1) ? va[j].y : (c == 2) ? va[j].z : va[j].w;
            if (binOf(v) >= bthr) {
                int p = atomicAdd(&scal[1], 1);
                if (p < CAP) cand[p] = make_uint2(fkey(v), (unsigned)(col0 + c));
            }
        }
    }
    __syncthreads();

    // rank (key desc, col asc)
    int C = min(scal[1], CAP);
    #pragma unroll
    for (int o = 0; o < 2; o++) {
        int t = tid + o * 256;
        if (t < C) {
            uint2 me = cand[t];
            int rk = 0;
            for (int c = 0; c < C; c++) {
                uint2 cd = cand[c];
                rk += (cd.x > me.x || (cd.x == me.x && (int)cd.y < (int)me.y)) ? 1 : 0;
            }
            if (rk < THR) topidx[(size_t)r * THR + rk] = (int)me.y;
        }
    }
}

// ---------------- mixloss: register-prefetched bf16 gathers ----------------
__global__ __launch_bounds__(512, 4) void mixloss(
    const unsigned short* __restrict__ Pb, const float* __restrict__ pool_n,
    const float* __restrict__ proj_b,
    const float* __restrict__ negsum, const float* __restrict__ refl,
    const float* __restrict__ posd, const int* __restrict__ topidx,
    const int* __restrict__ idx1, const int* __restrict__ idx2,
    float* __restrict__ out) {
    __shared__ int top_sh[THR];
    __shared__ int idx_sh[2 * SS];
    __shared__ float pn2[SS * 17];
    __shared__ float pdt[SS * 17];
    __shared__ float red2[8];

    int tid = threadIdx.x, w = tid >> 6, l = tid & 63;
    int r = blockIdx.x;
    int i = r & (NN - 1);
    const int* idxp = ((r >= NN) ? idx2 : idx1) + (size_t)i * (2 * SS);

    if (tid < THR) top_sh[tid] = topidx[(size_t)r * THR + tid];
    if (tid < 2 * SS) idx_sh[tid] = idxp[tid];

    int gid = tid >> 4, sub = tid & 15, d0 = sub * 8;
    float qv[8], bv[8];
    *(float4*)&qv[0] = *(const float4*)(pool_n + (size_t)r * DD + d0);
    *(float4*)&qv[4] = *(const float4*)(pool_n + (size_t)r * DD + d0 + 4);
    *(float4*)&bv[0] = *(const float4*)(proj_b + d0);
    *(float4*)&bv[4] = *(const float4*)(proj_b + d0 + 4);
    __syncthreads();

    // prefetch: up to 5 t's per thread, all loads issued before any use
    s16x8 xr[5], yr[5];
    #pragma unroll
    for (int k = 0; k < 5; k++) {
        int t = gid + 32 * k;
        if (t < SS) {
            xr[k] = *(const s16x8*)(Pb + (size_t)top_sh[idx_sh[t]] * DD + d0);
            yr[k] = *(const s16x8*)(Pb + (size_t)top_sh[idx_sh[t + SS]] * DD + d0);
        }
    }

    #pragma unroll
    for (int k = 0; k < 5; k++) {
        int t = gid + 32 * k;
        if (t < SS) {
            float n2 = 0.f, dt = 0.f;
            #pragma unroll
            for (int kk = 0; kk < 8; kk++) {
                float h = fmaf(0.2f, bf2f((unsigned short)xr[k][kk]),
                          fmaf(0.8f, bf2f((unsigned short)yr[k][kk]), bv[kk]));
                n2 = fmaf(h, h, n2);
                dt = fmaf(h, qv[kk], dt);
            }
            pn2[t * 17 + sub] = n2;
            pdt[t * 17 + sub] = dt;
        }
    }
    __syncthreads();

    // phase 2: thread t reduces its 16 partials
    float wsum = 0.f;
    if (tid < SS) {
        float n2 = 0.f, dt = 0.f;
        #pragma unroll
        for (int k = 0; k < 16; k++) {
            n2 += pn2[tid * 17 + k];
            dt += pdt[tid * 17 + k];
        }
        wsum = __builtin_exp2f(EXP2C * dt * rsqrtf(fmaxf(n2, 1e-24f)));
    }
    #pragma unroll
    for (int mask = 1; mask < 64; mask <<= 1) wsum += __shfl_xor(wsum, mask);
    if (l == 0) red2[w] = wsum;
    __syncthreads();
    if (tid == 0) {
        float negm = red2[0] + red2[1] + red2[2] + red2[3]
                   + red2[4] + red2[5] + red2[6] + red2[7];
        float den = negsum[r] + negm - refl[r];
        float loss = logf(den) - 2.0f * posd[r];
        atomicAdd(out, loss * (1.0f / 4096.0f));
    }
}

extern "C" void kernel_launch(void* const* d_in, const int* in_sizes, int n_in,
                              void* d_out, int out_size, void* d_ws, size_t ws_size,
                              hipStream_t stream) {
    const float* z1  = (const float*)d_in[0];
    const float* z2  = (const float*)d_in[1];
    const float* pw  = (const float*)d_in[2];
    const float* pb  = (const float*)d_in[3];
    const int* idx1  = (const int*)d_in[4];
    const int* idx2  = (const int*)d_in[5];
    float* out = (float*)d_out;

    float* wsf = (float*)d_ws;
    float* pool_n  = wsf + OFF_POOLN;
    float* wtT     = wsf + OFF_WTT;
    unsigned short* Pb = (unsigned short*)(wsf + OFF_PB);
    float* negs    = wsf + OFF_NEG;
    float* rfl     = wsf + OFF_REFL;
    float* psd     = wsf + OFF_POSD;
    int*   topi    = (int*)(wsf + OFF_TOPI);
    unsigned short* poolb = (unsigned short*)(wsf + OFF_POOLB);
    float* sims    = wsf + OFF_SIMS;

    hipMemsetAsync(d_out, 0, sizeof(float), stream);

    prep_norm<<<PP, 64, 0, stream>>>(z1, z2, pool_n, poolb);
    prep_wt<<<64, 256, 0, stream>>>(pw, wtT);
    prep_proj<<<PP / 8, 256, 0, stream>>>(z1, z2, wtT, Pb);
    gram_mfma<<<1024, 256, 0, stream>>>(poolb, sims, rfl, psd);
    rowselect<<<PP, 256, 0, stream>>>(sims, topi, negs);
    mixloss<<<PP, 512, 0, stream>>>(Pb, pool_n, pb, negs, rfl, psd, topi,
                                    idx1, idx2, out);
}

// Round 13
// 98.609 us; speedup vs baseline: 1.7101x; 1.4034x over previous
//
#include <hip/hip_runtime.h>
#include <math.h>

#define NN 2048
#define PP 4096
#define DD 128
#define SS 150
#define THR 204
#define CAP 512
#define EXP2C 2.8853900817779268f   // 2/ln(2): exp(2x) = 2^(EXP2C*x)

typedef float f32x4 __attribute__((ext_vector_type(4)));
typedef short s16x8 __attribute__((ext_vector_type(8)));

// ws layout (float offsets) — bf16 arrays are 4096*128 u16 = 262144 floats each
#define OFF_POOLN 0          // 524288 f32
#define OFF_WTT   524288     // 16384 f32
#define OFF_PB    540672     // 262144 floats (bf16 projected pool)
#define OFF_NEG   802816     // 4096
#define OFF_REFL  806912     // 4096
#define OFF_POSD  811008     // 4096
#define OFF_TOPI  815104     // 835584 ints
#define OFF_POOLB 1650688    // 262144 floats (bf16 normalized pool)
#define OFF_SIMS  1912832    // 4096*4096 f32 = 64 MB
#define OFF_LOSS  18690048   // 4096 f32 per-row losses

__device__ __forceinline__ unsigned fkey(float v) {
    unsigned u = __float_as_uint(v);
    return u ^ (unsigned)(((int)u >> 31) | 0x80000000);
}
__device__ __forceinline__ unsigned short f2bf(float f) {
    unsigned u = __float_as_uint(f);
    u = (u + 0x7FFFu + ((u >> 16) & 1u)) >> 16;
    return (unsigned short)u;
}
__device__ __forceinline__ float bf2f(unsigned short h) {
    return __uint_as_float((unsigned)h << 16);
}
// value-linear monotone bin over [-1,1]: identical expression everywhere
__device__ __forceinline__ int binOf(float v) {
    int b = (int)fmaf(v, 512.f, 512.f);
    return min(max(b, 0), 1023);
}

// ---------------- prep: normalize pool rows -> f32 + bf16 ----------------
__global__ void prep_norm(const float* __restrict__ z1, const float* __restrict__ z2,
                          float* __restrict__ pool_n, unsigned short* __restrict__ poolb) {
    int b = blockIdx.x;
    int l = threadIdx.x;
    const float* src = (b < NN) ? z1 + (size_t)b * DD : z2 + (size_t)(b - NN) * DD;
    float2 v = *(const float2*)(src + 2 * l);
    float ss = v.x * v.x + v.y * v.y;
    #pragma unroll
    for (int mask = 1; mask < 64; mask <<= 1) ss += __shfl_xor(ss, mask);
    float inv = 1.0f / fmaxf(sqrtf(ss), 1e-12f);
    float2 nv; nv.x = v.x * inv; nv.y = v.y * inv;
    *(float2*)(pool_n + (size_t)b * DD + 2 * l) = nv;
    ((unsigned*)poolb)[(size_t)b * 64 + l] =
        (unsigned)f2bf(nv.x) | ((unsigned)f2bf(nv.y) << 16);
}

// ---------------- prep: transpose proj_w (fp32), layout [k][d] ----------------
__global__ void prep_wt(const float* __restrict__ pw, float* __restrict__ wtT) {
    int e = blockIdx.x * 256 + threadIdx.x;
    int k = e >> 7, d = e & 127;
    wtT[e] = pw[d * DD + k];
}

// ---------------- prep: Pb = bf16(z_pool @ W^T) ----------------
__global__ __launch_bounds__(256, 4) void prep_proj(
    const float* __restrict__ z1, const float* __restrict__ z2,
    const float* __restrict__ wtT, unsigned short* __restrict__ Pb) {
    __shared__ float z_sh[8][DD];
    int tid = threadIdx.x;
    int r0 = blockIdx.x * 8;
    for (int e = tid; e < 8 * DD; e += 256) {
        int rr = r0 + (e >> 7);
        z_sh[e >> 7][e & 127] = (rr < NN) ? z1[(size_t)rr * DD + (e & 127)]
                                          : z2[(size_t)(rr - NN) * DD + (e & 127)];
    }
    __syncthreads();
    int d = tid & 127, h = tid >> 7;
    float a0 = 0.f, a1 = 0.f, a2 = 0.f, a3 = 0.f;
    for (int k = 0; k < DD; k++) {
        float wv = wtT[k * DD + d];
        a0 += z_sh[4 * h + 0][k] * wv;
        a1 += z_sh[4 * h + 1][k] * wv;
        a2 += z_sh[4 * h + 2][k] * wv;
        a3 += z_sh[4 * h + 3][k] * wv;
    }
    Pb[(size_t)(r0 + 4 * h + 0) * DD + d] = f2bf(a0);
    Pb[(size_t)(r0 + 4 * h + 1) * DD + d] = f2bf(a1);
    Pb[(size_t)(r0 + 4 * h + 2) * DD + d] = f2bf(a2);
    Pb[(size_t)(r0 + 4 * h + 3) * DD + d] = f2bf(a3);
}

// ---------------- MFMA gram -> f32 sims; refl/posd on diag blocks ----------------
#define LDA 136
__global__ __launch_bounds__(256) void gram_mfma(
    const unsigned short* __restrict__ poolb, float* __restrict__ sims,
    float* __restrict__ refl, float* __restrict__ posd) {
    __shared__ short tiles[2 * 128 * LDA];
    short* As = tiles;
    short* Bs = tiles + 128 * LDA;

    int tid = threadIdx.x;
    int bi = blockIdx.x >> 5, bj = blockIdx.x & 31;
    int r0 = bi * 128, c0 = bj * 128;

    const unsigned short* gA = poolb + (size_t)r0 * DD;
    const unsigned short* gB = poolb + (size_t)c0 * DD;
    #pragma unroll
    for (int it = 0; it < 8; it++) {
        int g = it * 256 + tid;
        int row = g >> 4, ch = (g & 15) * 8;
        *(s16x8*)&As[row * LDA + ch] = *(const s16x8*)(gA + row * DD + ch);
        *(s16x8*)&Bs[row * LDA + ch] = *(const s16x8*)(gB + row * DD + ch);
    }
    __syncthreads();

    int l = tid & 63, w = tid >> 6;
    int wr = (w >> 1) * 64, wc = (w & 1) * 64;
    int lr = l & 15, lk = (l >> 4) * 8;

    f32x4 zero = {0.f, 0.f, 0.f, 0.f};
    f32x4 acc[4][4];
    #pragma unroll
    for (int m = 0; m < 4; m++)
        #pragma unroll
        for (int n = 0; n < 4; n++) acc[m][n] = zero;

    #pragma unroll
    for (int kk = 0; kk < 4; kk++) {
        int ko = kk * 32 + lk;
        s16x8 av[4], bv[4];
        #pragma unroll
        for (int m = 0; m < 4; m++)
            av[m] = *(const s16x8*)&As[(wr + m * 16 + lr) * LDA + ko];
        #pragma unroll
        for (int n = 0; n < 4; n++)
            bv[n] = *(const s16x8*)&Bs[(wc + n * 16 + lr) * LDA + ko];
        #pragma unroll
        for (int m = 0; m < 4; m++)
            #pragma unroll
            for (int n = 0; n < 4; n++)
                acc[m][n] = __builtin_amdgcn_mfma_f32_16x16x32_bf16(av[m], bv[n], acc[m][n], 0, 0, 0);
    }

    int fq = (l >> 4) * 4, fr = l & 15;

    #pragma unroll
    for (int m = 0; m < 4; m++)
        #pragma unroll
        for (int n = 0; n < 4; n++) {
            int grow = r0 + wr + m * 16 + fq;
            int gcol = c0 + wc + n * 16 + fr;
            size_t base = (size_t)grow * PP + gcol;
            #pragma unroll
            for (int reg = 0; reg < 4; reg++)
                sims[base + (size_t)reg * PP] = acc[m][n][reg];
        }

    if (r0 == c0 || c0 == (r0 ^ NN)) {
        #pragma unroll
        for (int m = 0; m < 4; m++)
            #pragma unroll
            for (int n = 0; n < 4; n++) {
                int grow = r0 + wr + m * 16 + fq;
                int gcol = c0 + wc + n * 16 + fr;
                #pragma unroll
                for (int reg = 0; reg < 4; reg++) {
                    float v = acc[m][n][reg];
                    if (gcol == grow + reg) refl[gcol] = v;
                    if (gcol == ((grow + reg) ^ NN)) posd[grow + reg] = v;
                }
            }
    }
}

// ---------------- top-204 select + negsum; single 1024-bin value-linear hist ----------------
__global__ __launch_bounds__(256) void rowselect(
    const float* __restrict__ sims, int* __restrict__ topidx,
    float* __restrict__ negsum) {
    __shared__ int hist[2][1024];        // 8 KB, 2 copies (tid>>7)
    __shared__ uint2 cand[CAP];
    __shared__ float part[4];
    __shared__ int scal[2];              // 0:bin  1:cnt

    int tid = threadIdx.x, w = tid >> 6, l = tid & 63;
    int hs = tid >> 7;
    int r = blockIdx.x;
    const float4* rp = (const float4*)(sims + (size_t)r * PP);

    float4 va[4];
    #pragma unroll
    for (int j = 0; j < 4; j++) va[j] = rp[tid + j * 256];

    // negsum: exp-sum of full row
    float es = 0.f;
    #pragma unroll
    for (int j = 0; j < 4; j++) {
        es += __builtin_exp2f(EXP2C * va[j].x) + __builtin_exp2f(EXP2C * va[j].y)
            + __builtin_exp2f(EXP2C * va[j].z) + __builtin_exp2f(EXP2C * va[j].w);
    }
    #pragma unroll
    for (int mask = 1; mask < 64; mask <<= 1) es += __shfl_xor(es, mask);
    if (l == 0) part[w] = es;

    #pragma unroll
    for (int q = 0; q < 4; q++) hist[0][tid + q * 256] = 0;
    #pragma unroll
    for (int q = 0; q < 4; q++) hist[1][tid + q * 256] = 0;
    if (tid == 0) scal[1] = 0;
    __syncthreads();
    if (tid == 0) negsum[r] = part[0] + part[1] + part[2] + part[3];

    // one hist pass on value-linear bins
    #pragma unroll
    for (int j = 0; j < 4; j++) {
        atomicAdd(&hist[hs][binOf(va[j].x)], 1);
        atomicAdd(&hist[hs][binOf(va[j].y)], 1);
        atomicAdd(&hist[hs][binOf(va[j].z)], 1);
        atomicAdd(&hist[hs][binOf(va[j].w)], 1);
    }
    __syncthreads();

    // scan: wave 0; lane l owns bins [l*16, l*16+16)
    if (w == 0) {
        int b16[16];
        int s = 0;
        #pragma unroll
        for (int q = 0; q < 4; q++) {
            int4 h0 = ((const int4*)hist[0])[l * 4 + q];
            int4 h1 = ((const int4*)hist[1])[l * 4 + q];
            b16[q * 4 + 0] = h0.x + h1.x; b16[q * 4 + 1] = h0.y + h1.y;
            b16[q * 4 + 2] = h0.z + h1.z; b16[q * 4 + 3] = h0.w + h1.w;
            s += b16[q * 4] + b16[q * 4 + 1] + b16[q * 4 + 2] + b16[q * 4 + 3];
        }
        int suf = s;
        #pragma unroll
        for (int off = 1; off < 64; off <<= 1) {
            int x = __shfl_down(suf, off);
            if (l + off < 64) suf += x;
        }
        int cum = suf - s;                 // strictly above this lane's bins
        #pragma unroll
        for (int j = 15; j >= 0; j--) {
            if (cum < THR && THR <= cum + b16[j]) scal[0] = l * 16 + j;
            cum += b16[j];
        }
    }
    __syncthreads();
    int bthr = scal[0];

    // collect candidates: bin >= bthr (identical binOf expression -> consistent)
    #pragma unroll
    for (int j = 0; j < 4; j++) {
        int col0 = (tid + j * 256) * 4;
        #pragma unroll
        for (int c = 0; c < 4; c++) {
            float v = (c == 0) ? va[j].x : (c == 1) ? va[j].y : (c == 2) ? va[j].z : va[j].w;
            if (binOf(v) >= bthr) {
                int p = atomicAdd(&scal[1], 1);
                if (p < CAP) cand[p] = make_uint2(fkey(v), (unsigned)(col0 + c));
            }
        }
    }
    __syncthreads();

    // rank (key desc, col asc)
    int C = min(scal[1], CAP);
    #pragma unroll
    for (int o = 0; o < 2; o++) {
        int t = tid + o * 256;
        if (t < C) {
            uint2 me = cand[t];
            int rk = 0;
            for (int c = 0; c < C; c++) {
                uint2 cd = cand[c];
                rk += (cd.x > me.x || (cd.x == me.x && (int)cd.y < (int)me.y)) ? 1 : 0;
            }
            if (rk < THR) topidx[(size_t)r * THR + rk] = (int)me.y;
        }
    }
}

// ---------------- mixloss: per-row loss store (no global atomic) ----------------
__global__ __launch_bounds__(512, 4) void mixloss(
    const unsigned short* __restrict__ Pb, const float* __restrict__ pool_n,
    const float* __restrict__ proj_b,
    const float* __restrict__ negsum, const float* __restrict__ refl,
    const float* __restrict__ posd, const int* __restrict__ topidx,
    const int* __restrict__ idx1, const int* __restrict__ idx2,
    float* __restrict__ losses) {
    __shared__ int top_sh[THR];
    __shared__ int idx_sh[2 * SS];
    __shared__ float pn2[SS * 17];
    __shared__ float pdt[SS * 17];
    __shared__ float red2[8];

    int tid = threadIdx.x, w = tid >> 6, l = tid & 63;
    int r = blockIdx.x;
    int i = r & (NN - 1);
    const int* idxp = ((r >= NN) ? idx2 : idx1) + (size_t)i * (2 * SS);

    if (tid < THR) top_sh[tid] = topidx[(size_t)r * THR + tid];
    if (tid < 2 * SS) idx_sh[tid] = idxp[tid];

    int gid = tid >> 4, sub = tid & 15, d0 = sub * 8;
    float qv[8], bv[8];
    *(float4*)&qv[0] = *(const float4*)(pool_n + (size_t)r * DD + d0);
    *(float4*)&qv[4] = *(const float4*)(pool_n + (size_t)r * DD + d0 + 4);
    *(float4*)&bv[0] = *(const float4*)(proj_b + d0);
    *(float4*)&bv[4] = *(const float4*)(proj_b + d0 + 4);
    __syncthreads();

    // prefetch: 5 t's per thread, UNCONDITIONAL clamped loads (batch-issued)
    s16x8 xr[5], yr[5];
    #pragma unroll
    for (int k = 0; k < 5; k++) {
        int t = gid + 32 * k;
        int tc = (t < SS) ? t : (SS - 1);
        xr[k] = *(const s16x8*)(Pb + (size_t)top_sh[idx_sh[tc]] * DD + d0);
        yr[k] = *(const s16x8*)(Pb + (size_t)top_sh[idx_sh[tc + SS]] * DD + d0);
    }

    #pragma unroll
    for (int k = 0; k < 5; k++) {
        int t = gid + 32 * k;
        float n2 = 0.f, dt = 0.f;
        #pragma unroll
        for (int kk = 0; kk < 8; kk++) {
            float h = fmaf(0.2f, bf2f((unsigned short)xr[k][kk]),
                      fmaf(0.8f, bf2f((unsigned short)yr[k][kk]), bv[kk]));
            n2 = fmaf(h, h, n2);
            dt = fmaf(h, qv[kk], dt);
        }
        if (t < SS) {
            pn2[t * 17 + sub] = n2;
            pdt[t * 17 + sub] = dt;
        }
    }
    __syncthreads();

    // phase 2: thread t reduces its 16 partials
    float wsum = 0.f;
    if (tid < SS) {
        float n2 = 0.f, dt = 0.f;
        #pragma unroll
        for (int k = 0; k < 16; k++) {
            n2 += pn2[tid * 17 + k];
            dt += pdt[tid * 17 + k];
        }
        wsum = __builtin_exp2f(EXP2C * dt * rsqrtf(fmaxf(n2, 1e-24f)));
    }
    #pragma unroll
    for (int mask = 1; mask < 64; mask <<= 1) wsum += __shfl_xor(wsum, mask);
    if (l == 0) red2[w] = wsum;
    __syncthreads();
    if (tid == 0) {
        float negm = red2[0] + red2[1] + red2[2] + red2[3]
                   + red2[4] + red2[5] + red2[6] + red2[7];
        float den = negsum[r] + negm - refl[r];
        losses[r] = logf(den) - 2.0f * posd[r];
    }
}

// ---------------- final: sum 4096 losses -> out ----------------
__global__ __launch_bounds__(1024) void reduce_loss(
    const float* __restrict__ losses, float* __restrict__ out) {
    __shared__ float ws[16];
    int tid = threadIdx.x, w = tid >> 6, l = tid & 63;
    float s = losses[tid] + losses[tid + 1024] + losses[tid + 2048] + losses[tid + 3072];
    #pragma unroll
    for (int mask = 1; mask < 64; mask <<= 1) s += __shfl_xor(s, mask);
    if (l == 0) ws[w] = s;
    __syncthreads();
    if (tid == 0) {
        float tot = 0.f;
        #pragma unroll
        for (int q = 0; q < 16; q++) tot += ws[q];
        out[0] = tot * (1.0f / 4096.0f);
    }
}

extern "C" void kernel_launch(void* const* d_in, const int* in_sizes, int n_in,
                              void* d_out, int out_size, void* d_ws, size_t ws_size,
                              hipStream_t stream) {
    const float* z1  = (const float*)d_in[0];
    const float* z2  = (const float*)d_in[1];
    const float* pw  = (const float*)d_in[2];
    const float* pb  = (const float*)d_in[3];
    const int* idx1  = (const int*)d_in[4];
    const int* idx2  = (const int*)d_in[5];
    float* out = (float*)d_out;

    float* wsf = (float*)d_ws;
    float* pool_n  = wsf + OFF_POOLN;
    float* wtT     = wsf + OFF_WTT;
    unsigned short* Pb = (unsigned short*)(wsf + OFF_PB);
    float* negs    = wsf + OFF_NEG;
    float* rfl     = wsf + OFF_REFL;
    float* psd     = wsf + OFF_POSD;
    int*   topi    = (int*)(wsf + OFF_TOPI);
    unsigned short* poolb = (unsigned short*)(wsf + OFF_POOLB);
    float* sims    = wsf + OFF_SIMS;
    float* losses  = wsf + OFF_LOSS;

    prep_norm<<<PP, 64, 0, stream>>>(z1, z2, pool_n, poolb);
    prep_wt<<<64, 256, 0, stream>>>(pw, wtT);
    prep_proj<<<PP / 8, 256, 0, stream>>>(z1, z2, wtT, Pb);
    gram_mfma<<<1024, 256, 0, stream>>>(poolb, sims, rfl, psd);
    rowselect<<<PP, 256, 0, stream>>>(sims, topi, negs);
    mixloss<<<PP, 512, 0, stream>>>(Pb, pool_n, pb, negs, rfl, psd, topi,
                                    idx1, idx2, losses);
    reduce_loss<<<1, 1024, 0, stream>>>(losses, out);
}